// Round 1
// baseline (8113.293 us; speedup 1.0000x reference)
//
#include <hip/hip_runtime.h>
#include <math.h>

#define B_ 32
#define N_ 512
#define D_ 768
#define L_ 2
#define NBR_ 4
#define FH_ 256
#define NC_ 2

static constexpr float kInvSqrtD = 0.03608439182435161f; // 1/sqrt(768)

// ---------------------------------------------------------------------------
// GEMM1 (NN): C[M,N] = A[M,K] @ W[K,N], all row-major. M=16384, N=K=768.
// 64x64 block tile, BK=16, 256 threads, 4x4 per thread.
// ---------------------------------------------------------------------------
__global__ __launch_bounds__(256) void gemm_nn(const float* __restrict__ A,
                                               const float* __restrict__ W,
                                               float* __restrict__ C,
                                               int M, int N, int K) {
  __shared__ float As[16][65];
  __shared__ float Bs[16][64];
  const int tid = threadIdx.x;
  const int bm = blockIdx.x * 64;
  const int bn = blockIdx.y * 64;
  const int tx = tid & 15, ty = tid >> 4;
  const int ar = tid >> 2;          // 0..63 A-tile row
  const int ac = (tid & 3) * 4;     // A-tile col group
  const int br = tid >> 4;          // 0..15 B-tile row
  const int bc = (tid & 15) * 4;    // B-tile col group
  float acc[4][4] = {};
  for (int k0 = 0; k0 < K; k0 += 16) {
    float4 av = *reinterpret_cast<const float4*>(&A[(size_t)(bm + ar) * K + k0 + ac]);
    As[ac + 0][ar] = av.x; As[ac + 1][ar] = av.y;
    As[ac + 2][ar] = av.z; As[ac + 3][ar] = av.w;
    float4 bv = *reinterpret_cast<const float4*>(&W[(size_t)(k0 + br) * N + bn + bc]);
    *reinterpret_cast<float4*>(&Bs[br][bc]) = bv;
    __syncthreads();
#pragma unroll
    for (int kk = 0; kk < 16; ++kk) {
      float a[4], bvv[4];
#pragma unroll
      for (int i = 0; i < 4; ++i) a[i] = As[kk][ty * 4 + i];
#pragma unroll
      for (int j = 0; j < 4; ++j) bvv[j] = Bs[kk][tx * 4 + j];
#pragma unroll
      for (int i = 0; i < 4; ++i)
#pragma unroll
        for (int j = 0; j < 4; ++j) acc[i][j] += a[i] * bvv[j];
    }
    __syncthreads();
  }
#pragma unroll
  for (int i = 0; i < 4; ++i) {
    float4 v = make_float4(acc[i][0], acc[i][1], acc[i][2], acc[i][3]);
    *reinterpret_cast<float4*>(&C[(size_t)(bm + ty * 4 + i) * N + bn + tx * 4]) = v;
  }
}

// ---------------------------------------------------------------------------
// GEMM2 (NT + gate epilogue): per batch b,
//   logits[q,k] = dot(Q[q,:], K[k,:]) / sqrt(D)
//   gate = clip(sigmoid(logits)*1.2 - 0.1, 0, 1) * pmask[q] * pmask[k]
// ---------------------------------------------------------------------------
__global__ __launch_bounds__(256) void gemm_nt_gate(const float* __restrict__ Q,
                                                    const float* __restrict__ Km,
                                                    const float* __restrict__ pmask,
                                                    float* __restrict__ gate) {
  const int b = blockIdx.z;
  const float* A  = Q  + (size_t)b * N_ * D_;
  const float* Bm = Km + (size_t)b * N_ * D_;
  float* G = gate + (size_t)b * N_ * N_;
  __shared__ float As[16][65];
  __shared__ float Bs[16][65];
  const int tid = threadIdx.x;
  const int bm = blockIdx.x * 64;  // q
  const int bn = blockIdx.y * 64;  // k
  const int tx = tid & 15, ty = tid >> 4;
  const int ar = tid >> 2;
  const int ac = (tid & 3) * 4;
  float acc[4][4] = {};
  for (int k0 = 0; k0 < D_; k0 += 16) {
    float4 av = *reinterpret_cast<const float4*>(&A[(size_t)(bm + ar) * D_ + k0 + ac]);
    As[ac + 0][ar] = av.x; As[ac + 1][ar] = av.y;
    As[ac + 2][ar] = av.z; As[ac + 3][ar] = av.w;
    float4 bv = *reinterpret_cast<const float4*>(&Bm[(size_t)(bn + ar) * D_ + k0 + ac]);
    Bs[ac + 0][ar] = bv.x; Bs[ac + 1][ar] = bv.y;
    Bs[ac + 2][ar] = bv.z; Bs[ac + 3][ar] = bv.w;
    __syncthreads();
#pragma unroll
    for (int kk = 0; kk < 16; ++kk) {
      float a[4], bvv[4];
#pragma unroll
      for (int i = 0; i < 4; ++i) a[i] = As[kk][ty * 4 + i];
#pragma unroll
      for (int j = 0; j < 4; ++j) bvv[j] = Bs[kk][tx * 4 + j];
#pragma unroll
      for (int i = 0; i < 4; ++i)
#pragma unroll
        for (int j = 0; j < 4; ++j) acc[i][j] += a[i] * bvv[j];
    }
    __syncthreads();
  }
  float pq[4], pk[4];
#pragma unroll
  for (int i = 0; i < 4; ++i) pq[i] = pmask[b * N_ + bm + ty * 4 + i];
#pragma unroll
  for (int j = 0; j < 4; ++j) pk[j] = pmask[b * N_ + bn + tx * 4 + j];
#pragma unroll
  for (int i = 0; i < 4; ++i) {
#pragma unroll
    for (int j = 0; j < 4; ++j) {
      float x = acc[i][j] * kInvSqrtD;
      float s = 1.0f / (1.0f + __expf(-x));
      float g = fminf(fmaxf(s * 1.2f - 0.1f, 0.0f), 1.0f);
      G[(size_t)(bm + ty * 4 + i) * N_ + bn + tx * 4 + j] = g * pq[i] * pk[j];
    }
  }
}

// ---------------------------------------------------------------------------
// Row sums of gate -> dis = deg > 0 ? deg^-0.5 : 0.  One wave per row.
// ---------------------------------------------------------------------------
__global__ __launch_bounds__(256) void row_dis(const float* __restrict__ gate,
                                               float* __restrict__ dis) {
  const int row  = blockIdx.x * 4 + (threadIdx.x >> 6);  // 0..B*N-1
  const int lane = threadIdx.x & 63;
  const float* g = gate + (size_t)row * N_;
  float s = 0.0f;
  for (int t = lane; t < N_; t += 64) s += g[t];
#pragma unroll
  for (int off = 32; off; off >>= 1) s += __shfl_down(s, off, 64);
  if (lane == 0) dis[row] = (s > 0.0f) ? rsqrtf(s) : 0.0f;
}

// ---------------------------------------------------------------------------
// GEMM3 (TN aggregation): per batch b,
//   O[j,d] = dis[j] * sum_i (gate[i,j]*dis[i]) * F[i,d]
// ---------------------------------------------------------------------------
__global__ __launch_bounds__(256) void gemm_tn_agg(const float* __restrict__ gate,
                                                   const float* __restrict__ dis,
                                                   const float* __restrict__ Fin,
                                                   float* __restrict__ Fout) {
  const int b = blockIdx.z;
  const float* G  = gate + (size_t)b * N_ * N_;
  const float* F  = Fin  + (size_t)b * N_ * D_;
  float*       O  = Fout + (size_t)b * N_ * D_;
  const float* ds = dis + (size_t)b * N_;
  __shared__ float Gs[16][64];
  __shared__ float Fs[16][64];
  const int tid = threadIdx.x;
  const int bj = blockIdx.x * 64;  // output node j
  const int bd = blockIdx.y * 64;  // feature d
  const int tx = tid & 15, ty = tid >> 4;
  const int kr = tid >> 4;          // 0..15 (i offset)
  const int cc = (tid & 15) * 4;    // col group
  float acc[4][4] = {};
  for (int i0 = 0; i0 < N_; i0 += 16) {
    float s = ds[i0 + kr];
    float4 gv = *reinterpret_cast<const float4*>(&G[(size_t)(i0 + kr) * N_ + bj + cc]);
    gv.x *= s; gv.y *= s; gv.z *= s; gv.w *= s;
    *reinterpret_cast<float4*>(&Gs[kr][cc]) = gv;
    float4 fv = *reinterpret_cast<const float4*>(&F[(size_t)(i0 + kr) * D_ + bd + cc]);
    *reinterpret_cast<float4*>(&Fs[kr][cc]) = fv;
    __syncthreads();
#pragma unroll
    for (int kk = 0; kk < 16; ++kk) {
      float a[4], fvv[4];
#pragma unroll
      for (int i = 0; i < 4; ++i) a[i] = Gs[kk][ty * 4 + i];
#pragma unroll
      for (int j = 0; j < 4; ++j) fvv[j] = Fs[kk][tx * 4 + j];
#pragma unroll
      for (int i = 0; i < 4; ++i)
#pragma unroll
        for (int j = 0; j < 4; ++j) acc[i][j] += a[i] * fvv[j];
    }
    __syncthreads();
  }
#pragma unroll
  for (int i = 0; i < 4; ++i) {
    float dj = ds[bj + ty * 4 + i];
    float4 v = make_float4(acc[i][0] * dj, acc[i][1] * dj, acc[i][2] * dj, acc[i][3] * dj);
    *reinterpret_cast<float4*>(&O[(size_t)(bj + ty * 4 + i) * D_ + bd + tx * 4]) = v;
  }
}

// ---------------------------------------------------------------------------
// Head: per batch b (block), branch i: retain/pps mix at node N-1, then MLP.
// ---------------------------------------------------------------------------
__global__ __launch_bounds__(256) void head_kernel(const float* __restrict__ feature,
                                                   const float* __restrict__ feat1,
                                                   const float* __restrict__ feat2,
                                                   const float* __restrict__ proj_w,
                                                   const float* __restrict__ proj_b,
                                                   const float* __restrict__ fc1_w,
                                                   const float* __restrict__ fc1_b,
                                                   const float* __restrict__ fc2_w,
                                                   const float* __restrict__ fc2_b,
                                                   const float* __restrict__ fcf_w,
                                                   const float* __restrict__ fcf_b,
                                                   float* __restrict__ out, int branch) {
  const int b = blockIdx.x;
  __shared__ float p[3][D_];
  __shared__ float x[D_];
  __shared__ float h1[FH_];
  __shared__ float h2[FH_];
  __shared__ float retain[3];
  const int tid = threadIdx.x;
  const size_t base = ((size_t)b * N_ + (N_ - 1)) * D_;
  for (int d = tid; d < D_; d += 256) {
    p[0][d] = feature[base + d];
    p[1][d] = feat1[base + d];
    p[2][d] = feat2[base + d];
  }
  __syncthreads();
  const int w = tid >> 6, lane = tid & 63;
  if (w < 3) {
    float s = 0.0f;
    for (int d = lane; d < D_; d += 64) s += p[w][d] * proj_w[d];
#pragma unroll
    for (int off = 32; off; off >>= 1) s += __shfl_down(s, off, 64);
    if (lane == 0) retain[w] = 1.0f / (1.0f + __expf(-(s + proj_b[0])));
  }
  __syncthreads();
  for (int d = tid; d < D_; d += 256)
    x[d] = retain[0] * p[0][d] + retain[1] * p[1][d] + retain[2] * p[2][d];
  __syncthreads();
  {
    float s = fc1_b[tid];
    const float* wrow = fc1_w + (size_t)tid * D_;
    for (int d = 0; d < D_; ++d) s += wrow[d] * x[d];
    h1[tid] = fmaxf(s, 0.0f);
  }
  __syncthreads();
  {
    float s = fc2_b[tid];
    const float* wrow = fc2_w + (size_t)tid * FH_;
    for (int d = 0; d < FH_; ++d) s += wrow[d] * h1[d];
    h2[tid] = fmaxf(s, 0.0f);
  }
  __syncthreads();
  if (w < NC_) {
    float s = 0.0f;
    for (int g = lane; g < FH_; g += 64) s += h2[g] * fcf_w[(size_t)w * FH_ + g];
#pragma unroll
    for (int off = 32; off; off >>= 1) s += __shfl_down(s, off, 64);
    if (lane == 0) out[((size_t)b * NBR_ + branch) * NC_ + w] = s + fcf_b[w];
  }
}

// ---------------------------------------------------------------------------
extern "C" void kernel_launch(void* const* d_in, const int* in_sizes, int n_in,
                              void* d_out, int out_size, void* d_ws, size_t ws_size,
                              hipStream_t stream) {
  (void)in_sizes; (void)n_in; (void)out_size; (void)ws_size;
  const float* pmask   = (const float*)d_in[0];
  const float* feature = (const float*)d_in[1];
  const float* Wq      = (const float*)d_in[2];
  const float* Wk      = (const float*)d_in[3];
  const float* proj_w  = (const float*)d_in[4];
  const float* proj_b  = (const float*)d_in[5];
  const float* fc1_w   = (const float*)d_in[6];
  const float* fc1_b   = (const float*)d_in[7];
  const float* fc2_w   = (const float*)d_in[8];
  const float* fc2_b   = (const float*)d_in[9];
  const float* fcf_w   = (const float*)d_in[10];
  const float* fcf_b   = (const float*)d_in[11];
  float* out = (float*)d_out;

  float* ws = (float*)d_ws;
  const size_t nBND = (size_t)B_ * N_ * D_;   // 12,582,912
  const size_t nBNN = (size_t)B_ * N_ * N_;   // 8,388,608
  float* Q     = ws;
  float* Kb    = Q + nBND;
  float* gate  = Kb + nBND;
  float* feat1 = gate + nBNN;
  float* feat2 = feat1 + nBND;
  float* dis   = feat2 + nBND;

  dim3 blk(256);
  dim3 g1((B_ * N_) / 64, D_ / 64);     // 256 x 12
  dim3 g2(N_ / 64, N_ / 64, B_);        // 8 x 8 x 32
  dim3 g3(N_ / 64, D_ / 64, B_);        // 8 x 12 x 32

  for (int i = 0; i < NBR_; ++i) {
    const float* fin = feature;
    float* fout = feat1;
    for (int l = 0; l < L_; ++l) {
      const float* wq = Wq + ((size_t)i * L_ + l) * D_ * D_;
      const float* wk = Wk + ((size_t)i * L_ + l) * D_ * D_;
      gemm_nn<<<g1, blk, 0, stream>>>(fin, wq, Q,  B_ * N_, D_, D_);
      gemm_nn<<<g1, blk, 0, stream>>>(fin, wk, Kb, B_ * N_, D_, D_);
      gemm_nt_gate<<<g2, blk, 0, stream>>>(Q, Kb, pmask, gate);
      row_dis<<<dim3((B_ * N_) / 4), blk, 0, stream>>>(gate, dis);
      gemm_tn_agg<<<g3, blk, 0, stream>>>(gate, dis, fin, fout);
      fin = fout;
      fout = feat2;
    }
    head_kernel<<<dim3(B_), blk, 0, stream>>>(feature, feat1, feat2,
        proj_w + (size_t)i * D_, proj_b + i,
        fc1_w + (size_t)i * FH_ * D_, fc1_b + (size_t)i * FH_,
        fc2_w + (size_t)i * FH_ * FH_, fc2_b + (size_t)i * FH_,
        fcf_w + (size_t)i * NC_ * FH_, fcf_b + (size_t)i * NC_,
        out, i);
  }
}

// Round 2
// 1272.977 us; speedup vs baseline: 6.3735x; 6.3735x over previous
//
#include <hip/hip_runtime.h>
#include <hip/hip_bf16.h>
#include <math.h>

#define B_ 32
#define N_ 512
#define D_ 768
#define L_ 2
#define NBR_ 4
#define FH_ 256
#define NC_ 2

typedef __attribute__((ext_vector_type(8))) short short8;
typedef __attribute__((ext_vector_type(4))) short short4v;
typedef __attribute__((ext_vector_type(4))) float f32x4;

static constexpr float kInvSqrtD = 0.03608439182435161f; // 1/sqrt(768)

__device__ __forceinline__ void gl2lds16(const void* g, void* l) {
  __builtin_amdgcn_global_load_lds(
      (const __attribute__((address_space(1))) unsigned int*)g,
      (__attribute__((address_space(3))) unsigned int*)l, 16, 0, 0);
}
__device__ __forceinline__ unsigned short f2bf(float f) {
  __hip_bfloat16 h = __float2bfloat16(f);
  return *reinterpret_cast<unsigned short*>(&h);
}
__device__ __forceinline__ float bf2f(unsigned short u) {
  unsigned int x = ((unsigned int)u) << 16;
  return __builtin_bit_cast(float, x);
}

// ---------------------------------------------------------------------------
// Shared NT-GEMM core: C128x128 += A[M,K] * BT[N,K]^T, bf16 in, fp32 acc.
// 256 threads = 4 waves, each wave owns a 64x64 quadrant (4x4 16x16 frags).
// LDS linear [128][32] staged via global_load_lds width-16.
// ---------------------------------------------------------------------------
__device__ __forceinline__ void nt_gemm_core(
    const unsigned short* __restrict__ A, const unsigned short* __restrict__ BT,
    int K, int bm, int bn, short* As, short* Bs, f32x4 (&acc)[4][4]) {
  const int tid = threadIdx.x;
  const int lane = tid & 63;
  const int w = tid >> 6, wr = w >> 1, wc = w & 1;
  const int srow = tid >> 2;        // 0..63
  const int scol = (tid & 3) * 8;   // 0,8,16,24
  const int kb = lane >> 4;         // 0..3
  const int fr = lane & 15;
  for (int k0 = 0; k0 < K; k0 += 32) {
    gl2lds16(A + (size_t)(bm + srow) * K + k0 + scol, As + tid * 8);
    gl2lds16(A + (size_t)(bm + 64 + srow) * K + k0 + scol, As + 2048 + tid * 8);
    gl2lds16(BT + (size_t)(bn + srow) * K + k0 + scol, Bs + tid * 8);
    gl2lds16(BT + (size_t)(bn + 64 + srow) * K + k0 + scol, Bs + 2048 + tid * 8);
    __syncthreads();
    short8 a[4], b[4];
#pragma unroll
    for (int m = 0; m < 4; ++m)
      a[m] = *reinterpret_cast<const short8*>(&As[(wr * 64 + m * 16 + fr) * 32 + kb * 8]);
#pragma unroll
    for (int n = 0; n < 4; ++n)
      b[n] = *reinterpret_cast<const short8*>(&Bs[(wc * 64 + n * 16 + fr) * 32 + kb * 8]);
#pragma unroll
    for (int m = 0; m < 4; ++m)
#pragma unroll
      for (int n = 0; n < 4; ++n)
        acc[m][n] = __builtin_amdgcn_mfma_f32_16x16x32_bf16(a[m], b[n], acc[m][n], 0, 0, 0);
    __syncthreads();
  }
}

// ---------------------------------------------------------------------------
// Projections: Q = feat @ WqT^T, K = feat @ WkT^T (z selects). bf16 out.
// ---------------------------------------------------------------------------
__global__ __launch_bounds__(256) void proj_kernel(
    const __hip_bfloat16* __restrict__ feat,
    const __hip_bfloat16* __restrict__ WqT, const __hip_bfloat16* __restrict__ WkT,
    __hip_bfloat16* __restrict__ Qb, __hip_bfloat16* __restrict__ Kb) {
  __shared__ short As[4096], Bs[4096];
  const unsigned short* A = (const unsigned short*)feat;
  const unsigned short* BT = (const unsigned short*)(blockIdx.z ? WkT : WqT);
  unsigned short* Out = (unsigned short*)(blockIdx.z ? Kb : Qb);
  const int bm = blockIdx.x * 128, bn = blockIdx.y * 128;
  f32x4 acc[4][4] = {};
  nt_gemm_core(A, BT, D_, bm, bn, As, Bs, acc);
  const int lane = threadIdx.x & 63, w = threadIdx.x >> 6;
  const int wr = w >> 1, wc = w & 1, kb = lane >> 4, fr = lane & 15;
#pragma unroll
  for (int m = 0; m < 4; ++m)
#pragma unroll
    for (int n = 0; n < 4; ++n)
#pragma unroll
      for (int r = 0; r < 4; ++r) {
        int row = bm + wr * 64 + m * 16 + kb * 4 + r;
        int col = bn + wc * 64 + n * 16 + fr;
        Out[(size_t)row * D_ + col] = f2bf(acc[m][n][r]);
      }
}

// ---------------------------------------------------------------------------
// Logits (operand-swapped): tile rows = k, cols = q -> writes G_T[k][q] bf16
// with gate epilogue; fused deg[q] column sums via shuffle + atomicAdd.
// ---------------------------------------------------------------------------
__global__ __launch_bounds__(256) void logits_kernel(
    const __hip_bfloat16* __restrict__ Kb, const __hip_bfloat16* __restrict__ Qb,
    const float* __restrict__ pmask, __hip_bfloat16* __restrict__ GT,
    float* __restrict__ deg) {
  __shared__ short As[4096], Bs[4096];
  const int b = blockIdx.z;
  const unsigned short* A = (const unsigned short*)Kb + (size_t)b * N_ * D_;
  const unsigned short* BT = (const unsigned short*)Qb + (size_t)b * N_ * D_;
  unsigned short* G = (unsigned short*)GT + (size_t)b * N_ * N_;
  const int bm = blockIdx.x * 128, bn = blockIdx.y * 128;
  f32x4 acc[4][4] = {};
  nt_gemm_core(A, BT, D_, bm, bn, As, Bs, acc);
  const int lane = threadIdx.x & 63, w = threadIdx.x >> 6;
  const int wr = w >> 1, wc = w & 1, kb = lane >> 4, fr = lane & 15;
  float colsum[4] = {0.f, 0.f, 0.f, 0.f};
#pragma unroll
  for (int m = 0; m < 4; ++m) {
    float pk[4];
#pragma unroll
    for (int r = 0; r < 4; ++r)
      pk[r] = pmask[b * N_ + bm + wr * 64 + m * 16 + kb * 4 + r];
#pragma unroll
    for (int n = 0; n < 4; ++n) {
      int col = bn + wc * 64 + n * 16 + fr;
      float pq = pmask[b * N_ + col];
#pragma unroll
      for (int r = 0; r < 4; ++r) {
        int row = bm + wr * 64 + m * 16 + kb * 4 + r;
        float x = acc[m][n][r] * kInvSqrtD;
        float s = 1.0f / (1.0f + __expf(-x));
        float g = fminf(fmaxf(s * 1.2f - 0.1f, 0.0f), 1.0f);
        float v = g * pk[r] * pq;
        G[(size_t)row * N_ + col] = f2bf(v);
        colsum[n] += v;
      }
    }
  }
#pragma unroll
  for (int n = 0; n < 4; ++n) {
    float s = colsum[n];
    s += __shfl_xor(s, 16, 64);
    s += __shfl_xor(s, 32, 64);
    if (lane < 16)
      atomicAdd(&deg[b * N_ + bn + wc * 64 + n * 16 + fr], s);
  }
}

// ---------------------------------------------------------------------------
// Aggregation: O[j][d] = dis_j * sum_i G_T[j][i] * F_T[d][i]  (F_T has dis_i
// folded in). Writes fp32 (rows >= 384, for head) and optionally bf16 (L1).
// ---------------------------------------------------------------------------
template <bool WBF>
__global__ __launch_bounds__(256) void agg_kernel(
    const __hip_bfloat16* __restrict__ GT, const __hip_bfloat16* __restrict__ FT,
    const float* __restrict__ dis, float* __restrict__ flast,
    __hip_bfloat16* __restrict__ fbf, int j_off) {
  __shared__ short As[4096], Bs[4096];
  const int b = blockIdx.z;
  const unsigned short* A = (const unsigned short*)GT + (size_t)b * N_ * N_;
  const unsigned short* BT = (const unsigned short*)FT + (size_t)b * D_ * N_;
  const int bm = j_off + blockIdx.x * 128, bn = blockIdx.y * 128;
  f32x4 acc[4][4] = {};
  nt_gemm_core(A, BT, N_, bm, bn, As, Bs, acc);
  const int lane = threadIdx.x & 63, w = threadIdx.x >> 6;
  const int wr = w >> 1, wc = w & 1, kb = lane >> 4, fr = lane & 15;
#pragma unroll
  for (int m = 0; m < 4; ++m) {
#pragma unroll
    for (int r = 0; r < 4; ++r) {
      int row = bm + wr * 64 + m * 16 + kb * 4 + r;
      float dj = dis[b * N_ + row];
#pragma unroll
      for (int n = 0; n < 4; ++n) {
        int col = bn + wc * 64 + n * 16 + fr;
        float v = acc[m][n][r] * dj;
        if (WBF)
          fbf[((size_t)b * N_ + row) * D_ + col] = __float2bfloat16(v);
        if (row >= 384)
          flast[((size_t)b * 128 + row - 384) * D_ + col] = v;
      }
    }
  }
}

// ---------------------------------------------------------------------------
// Transpose + dis-scale: F_T[b][d][i] = bf16(dis[b][i] * fin[b][i][d]).
// ---------------------------------------------------------------------------
template <bool BF16IN>
__global__ __launch_bounds__(256) void tscale_kernel(
    const void* __restrict__ fin, const float* __restrict__ dis,
    __hip_bfloat16* __restrict__ FT) {
  __shared__ float Ts[64][65];
  const int b = blockIdx.z;
  const int i0 = blockIdx.x * 64, d0 = blockIdx.y * 64;
  const int t = threadIdx.x;
  const int r16 = t >> 4, c4 = (t & 15) * 4;
#pragma unroll
  for (int p = 0; p < 4; ++p) {
    int i = r16 + p * 16;
    size_t idx = ((size_t)b * N_ + i0 + i) * D_ + d0 + c4;
    float v0, v1, v2, v3;
    if (BF16IN) {
      short4v sv = *reinterpret_cast<const short4v*>((const unsigned short*)fin + idx);
      v0 = bf2f((unsigned short)sv.x); v1 = bf2f((unsigned short)sv.y);
      v2 = bf2f((unsigned short)sv.z); v3 = bf2f((unsigned short)sv.w);
    } else {
      float4 fv = *reinterpret_cast<const float4*>((const float*)fin + idx);
      v0 = fv.x; v1 = fv.y; v2 = fv.z; v3 = fv.w;
    }
    Ts[i][c4 + 0] = v0; Ts[i][c4 + 1] = v1;
    Ts[i][c4 + 2] = v2; Ts[i][c4 + 3] = v3;
  }
  __syncthreads();
#pragma unroll
  for (int q = 0; q < 4; ++q) {
    int d = r16 + q * 16;
    short4v o;
#pragma unroll
    for (int e = 0; e < 4; ++e) {
      float dv = dis[b * N_ + i0 + c4 + e];
      o[e] = (short)f2bf(Ts[c4 + e][d] * dv);
    }
    *reinterpret_cast<short4v*>((unsigned short*)FT + ((size_t)b * D_ + d0 + d) * N_ + i0 + c4) = o;
  }
}

// ---------------------------------------------------------------------------
// Weight transpose-convert: WT[mat][e][d] = bf16(W[mat][d][e]).
// ---------------------------------------------------------------------------
__global__ __launch_bounds__(256) void wtrans_kernel(
    const float* __restrict__ W, __hip_bfloat16* __restrict__ WT) {
  __shared__ float Ts[64][65];
  const size_t mb = (size_t)blockIdx.z * D_ * D_;
  const int a0 = blockIdx.x * 64, b0 = blockIdx.y * 64;
  const int t = threadIdx.x;
  const int r16 = t >> 4, c4 = (t & 15) * 4;
#pragma unroll
  for (int p = 0; p < 4; ++p) {
    int r = r16 + p * 16;
    float4 fv = *reinterpret_cast<const float4*>(&W[mb + (size_t)(a0 + r) * D_ + b0 + c4]);
    Ts[r][c4 + 0] = fv.x; Ts[r][c4 + 1] = fv.y;
    Ts[r][c4 + 2] = fv.z; Ts[r][c4 + 3] = fv.w;
  }
  __syncthreads();
  unsigned short* O = (unsigned short*)WT;
#pragma unroll
  for (int q = 0; q < 4; ++q) {
    int e = r16 + q * 16;
    short4v o;
#pragma unroll
    for (int k = 0; k < 4; ++k) o[k] = (short)f2bf(Ts[c4 + k][e]);
    *reinterpret_cast<short4v*>(&O[mb + (size_t)(b0 + e) * D_ + a0 + c4]) = o;
  }
}

// ---------------------------------------------------------------------------
__global__ __launch_bounds__(256) void cvt_kernel(const float* __restrict__ src,
                                                  __hip_bfloat16* __restrict__ dst) {
  int i = blockIdx.x * 256 + threadIdx.x;
  float4 v = reinterpret_cast<const float4*>(src)[i];
  short4v o = {(short)f2bf(v.x), (short)f2bf(v.y), (short)f2bf(v.z), (short)f2bf(v.w)};
  reinterpret_cast<short4v*>(dst)[i] = o;
}

__global__ __launch_bounds__(256) void dis_kernel(const float* __restrict__ deg,
                                                  float* __restrict__ dis) {
  int i = blockIdx.x * 256 + threadIdx.x;
  float d = deg[i];
  dis[i] = d > 0.0f ? rsqrtf(d) : 0.0f;
}

// ---------------------------------------------------------------------------
// Head (fp32): retain mix at node N-1, then 3-layer MLP. One block per batch.
// ---------------------------------------------------------------------------
__global__ __launch_bounds__(256) void head_kernel(
    const float* __restrict__ feature, const float* __restrict__ f1last,
    const float* __restrict__ f2last, const float* __restrict__ proj_w,
    const float* __restrict__ proj_b, const float* __restrict__ fc1_w,
    const float* __restrict__ fc1_b, const float* __restrict__ fc2_w,
    const float* __restrict__ fc2_b, const float* __restrict__ fcf_w,
    const float* __restrict__ fcf_b, float* __restrict__ out, int branch) {
  const int b = blockIdx.x;
  __shared__ float p[3][D_];
  __shared__ float x[D_];
  __shared__ float h1[FH_];
  __shared__ float h2[FH_];
  __shared__ float retain[3];
  const int tid = threadIdx.x;
  const size_t base0 = ((size_t)b * N_ + (N_ - 1)) * D_;
  const size_t basel = ((size_t)b * 128 + 127) * D_;
  for (int d = tid; d < D_; d += 256) {
    p[0][d] = feature[base0 + d];
    p[1][d] = f1last[basel + d];
    p[2][d] = f2last[basel + d];
  }
  __syncthreads();
  const int w = tid >> 6, lane = tid & 63;
  if (w < 3) {
    float s = 0.0f;
    for (int d = lane; d < D_; d += 64) s += p[w][d] * proj_w[d];
#pragma unroll
    for (int off = 32; off; off >>= 1) s += __shfl_down(s, off, 64);
    if (lane == 0) retain[w] = 1.0f / (1.0f + __expf(-(s + proj_b[0])));
  }
  __syncthreads();
  for (int d = tid; d < D_; d += 256)
    x[d] = retain[0] * p[0][d] + retain[1] * p[1][d] + retain[2] * p[2][d];
  __syncthreads();
  {
    float s = fc1_b[tid];
    const float* wrow = fc1_w + (size_t)tid * D_;
    for (int d = 0; d < D_; ++d) s += wrow[d] * x[d];
    h1[tid] = fmaxf(s, 0.0f);
  }
  __syncthreads();
  {
    float s = fc2_b[tid];
    const float* wrow = fc2_w + (size_t)tid * FH_;
    for (int d = 0; d < FH_; ++d) s += wrow[d] * h1[d];
    h2[tid] = fmaxf(s, 0.0f);
  }
  __syncthreads();
  if (w < NC_) {
    float s = 0.0f;
    for (int g = lane; g < FH_; g += 64) s += h2[g] * fcf_w[(size_t)w * FH_ + g];
#pragma unroll
    for (int off = 32; off; off >>= 1) s += __shfl_down(s, off, 64);
    if (lane == 0) out[((size_t)b * NBR_ + branch) * NC_ + w] = s + fcf_b[w];
  }
}

// ---------------------------------------------------------------------------
extern "C" void kernel_launch(void* const* d_in, const int* in_sizes, int n_in,
                              void* d_out, int out_size, void* d_ws, size_t ws_size,
                              hipStream_t stream) {
  (void)in_sizes; (void)n_in; (void)out_size; (void)ws_size;
  const float* pmask   = (const float*)d_in[0];
  const float* feature = (const float*)d_in[1];
  const float* Wq      = (const float*)d_in[2];
  const float* Wk      = (const float*)d_in[3];
  const float* proj_w  = (const float*)d_in[4];
  const float* proj_b  = (const float*)d_in[5];
  const float* fc1_w   = (const float*)d_in[6];
  const float* fc1_b   = (const float*)d_in[7];
  const float* fc2_w   = (const float*)d_in[8];
  const float* fc2_b   = (const float*)d_in[9];
  const float* fcf_w   = (const float*)d_in[10];
  const float* fcf_b   = (const float*)d_in[11];
  float* out = (float*)d_out;

  const size_t nBND  = (size_t)B_ * N_ * D_;        // 12,582,912
  const size_t nW    = (size_t)NBR_ * L_ * D_ * D_; //  4,718,592
  const size_t nBNN  = (size_t)B_ * N_ * N_;        //  8,388,608
  const size_t nLast = (size_t)B_ * 128 * D_;       //  3,145,728

  char* p = (char*)d_ws;
  __hip_bfloat16* feat0 = (__hip_bfloat16*)p; p += nBND * 2;
  __hip_bfloat16* WqT   = (__hip_bfloat16*)p; p += nW * 2;
  __hip_bfloat16* WkT   = (__hip_bfloat16*)p; p += nW * 2;
  __hip_bfloat16* Qb    = (__hip_bfloat16*)p; p += nBND * 2;
  __hip_bfloat16* Kb    = (__hip_bfloat16*)p; p += nBND * 2;
  __hip_bfloat16* GT    = (__hip_bfloat16*)p; p += nBNN * 2;
  __hip_bfloat16* FT    = (__hip_bfloat16*)p; p += nBND * 2;
  __hip_bfloat16* f1bf  = (__hip_bfloat16*)p; p += nBND * 2;
  float* deg    = (float*)p; p += (size_t)B_ * N_ * 4;
  float* dis    = (float*)p; p += (size_t)B_ * N_ * 4;
  float* f1last = (float*)p; p += nLast * 4;
  float* f2last = (float*)p; p += nLast * 4;

  dim3 blk(256);
  cvt_kernel<<<dim3((unsigned)(nBND / 4 / 256)), blk, 0, stream>>>(feature, feat0);
  wtrans_kernel<<<dim3(12, 12, 8), blk, 0, stream>>>(Wq, WqT);
  wtrans_kernel<<<dim3(12, 12, 8), blk, 0, stream>>>(Wk, WkT);

  for (int i = 0; i < NBR_; ++i) {
    for (int l = 0; l < L_; ++l) {
      const size_t woff = ((size_t)i * L_ + l) * D_ * D_;
      const __hip_bfloat16* featbf = l ? f1bf : feat0;
      hipMemsetAsync(deg, 0, (size_t)B_ * N_ * 4, stream);
      proj_kernel<<<dim3(128, 6, 2), blk, 0, stream>>>(featbf, WqT + woff, WkT + woff, Qb, Kb);
      logits_kernel<<<dim3(4, 4, 32), blk, 0, stream>>>(Kb, Qb, pmask, GT, deg);
      dis_kernel<<<dim3(64), blk, 0, stream>>>(deg, dis);
      if (l == 0) {
        tscale_kernel<false><<<dim3(8, 12, 32), blk, 0, stream>>>(feature, dis, FT);
        agg_kernel<true><<<dim3(4, 6, 32), blk, 0, stream>>>(GT, FT, dis, f1last, f1bf, 0);
      } else {
        tscale_kernel<true><<<dim3(8, 12, 32), blk, 0, stream>>>(f1bf, dis, FT);
        agg_kernel<false><<<dim3(1, 6, 32), blk, 0, stream>>>(GT, FT, dis, f2last, nullptr, 384);
      }
    }
    head_kernel<<<dim3(B_), blk, 0, stream>>>(feature, f1last, f2last,
        proj_w + (size_t)i * D_, proj_b + i,
        fc1_w + (size_t)i * FH_ * D_, fc1_b + (size_t)i * FH_,
        fc2_w + (size_t)i * FH_ * FH_, fc2_b + (size_t)i * FH_,
        fcf_w + (size_t)i * NC_ * FH_, fcf_b + (size_t)i * NC_,
        out, i);
  }
}

// Round 3
// 1110.050 us; speedup vs baseline: 7.3089x; 1.1468x over previous
//
#include <hip/hip_runtime.h>
#include <hip/hip_bf16.h>
#include <math.h>

#define B_ 32
#define N_ 512
#define D_ 768
#define L_ 2
#define NBR_ 4
#define FH_ 256
#define NC_ 2

typedef __attribute__((ext_vector_type(8))) short short8;
typedef __attribute__((ext_vector_type(4))) short short4v;
typedef __attribute__((ext_vector_type(4))) float f32x4;

static constexpr float kInvSqrtD = 0.03608439182435161f; // 1/sqrt(768)

__device__ __forceinline__ void gl2lds16(const void* g, void* l) {
  __builtin_amdgcn_global_load_lds(
      (const __attribute__((address_space(1))) unsigned int*)g,
      (__attribute__((address_space(3))) unsigned int*)l, 16, 0, 0);
}
__device__ __forceinline__ unsigned short f2bf(float f) {
  __hip_bfloat16 h = __float2bfloat16(f);
  return *reinterpret_cast<unsigned short*>(&h);
}
__device__ __forceinline__ float bf2f(unsigned short u) {
  unsigned int x = ((unsigned int)u) << 16;
  return __builtin_bit_cast(float, x);
}

// ---------------------------------------------------------------------------
// Shared NT-GEMM core (verified): C128x128 += A[M,K] * BT[N,K]^T, bf16 in,
// fp32 acc. 256 threads = 4 waves, each wave a 64x64 quadrant (4x4 frags).
// LDS linear [128][32] staged via global_load_lds width-16. UNCHANGED.
// ---------------------------------------------------------------------------
__device__ __forceinline__ void nt_gemm_core(
    const unsigned short* __restrict__ A, const unsigned short* __restrict__ BT,
    int K, int bm, int bn, short* As, short* Bs, f32x4 (&acc)[4][4]) {
  const int tid = threadIdx.x;
  const int lane = tid & 63;
  const int w = tid >> 6, wr = w >> 1, wc = w & 1;
  const int srow = tid >> 2;        // 0..63
  const int scol = (tid & 3) * 8;   // 0,8,16,24
  const int kb = lane >> 4;         // 0..3
  const int fr = lane & 15;
  for (int k0 = 0; k0 < K; k0 += 32) {
    gl2lds16(A + (size_t)(bm + srow) * K + k0 + scol, As + tid * 8);
    gl2lds16(A + (size_t)(bm + 64 + srow) * K + k0 + scol, As + 2048 + tid * 8);
    gl2lds16(BT + (size_t)(bn + srow) * K + k0 + scol, Bs + tid * 8);
    gl2lds16(BT + (size_t)(bn + 64 + srow) * K + k0 + scol, Bs + 2048 + tid * 8);
    __syncthreads();
    short8 a[4], b[4];
#pragma unroll
    for (int m = 0; m < 4; ++m)
      a[m] = *reinterpret_cast<const short8*>(&As[(wr * 64 + m * 16 + fr) * 32 + kb * 8]);
#pragma unroll
    for (int n = 0; n < 4; ++n)
      b[n] = *reinterpret_cast<const short8*>(&Bs[(wc * 64 + n * 16 + fr) * 32 + kb * 8]);
#pragma unroll
    for (int m = 0; m < 4; ++m)
#pragma unroll
      for (int n = 0; n < 4; ++n)
        acc[m][n] = __builtin_amdgcn_mfma_f32_16x16x32_bf16(a[m], b[n], acc[m][n], 0, 0, 0);
    __syncthreads();
  }
}

// ---------------------------------------------------------------------------
// MT precompute: MT[z][e][d] = sum_c Wk[z][e][c] * Wq[z][d][c]  (= M^T where
// M = Wq Wk^T). One launch, z = branch*L+layer. bf16 out.
// ---------------------------------------------------------------------------
__global__ __launch_bounds__(256) void mt_kernel(
    const __hip_bfloat16* __restrict__ Wkbf, const __hip_bfloat16* __restrict__ Wqbf,
    __hip_bfloat16* __restrict__ MT) {
  __shared__ short As[4096], Bs[4096];
  const size_t zoff = (size_t)blockIdx.z * D_ * D_;
  const unsigned short* A = (const unsigned short*)Wkbf + zoff;
  const unsigned short* BT = (const unsigned short*)Wqbf + zoff;
  unsigned short* Out = (unsigned short*)MT + zoff;
  const int bm = blockIdx.x * 128, bn = blockIdx.y * 128;
  f32x4 acc[4][4] = {};
  nt_gemm_core(A, BT, D_, bm, bn, As, Bs, acc);
  const int lane = threadIdx.x & 63, w = threadIdx.x >> 6;
  const int wr = w >> 1, wc = w & 1, kb = lane >> 4, fr = lane & 15;
#pragma unroll
  for (int m = 0; m < 4; ++m)
#pragma unroll
    for (int n = 0; n < 4; ++n)
#pragma unroll
      for (int r = 0; r < 4; ++r) {
        int row = bm + wr * 64 + m * 16 + kb * 4 + r;
        int col = bn + wc * 64 + n * 16 + fr;
        Out[(size_t)row * D_ + col] = f2bf(acc[m][n][r]);
      }
}

// ---------------------------------------------------------------------------
// P = feat @ M  (via NT with BT = MT). bf16 out. M=16384, N=K=768.
// ---------------------------------------------------------------------------
__global__ __launch_bounds__(256) void p_kernel(
    const __hip_bfloat16* __restrict__ feat, const __hip_bfloat16* __restrict__ MT,
    __hip_bfloat16* __restrict__ P) {
  __shared__ short As[4096], Bs[4096];
  const unsigned short* A = (const unsigned short*)feat;
  const unsigned short* BT = (const unsigned short*)MT;
  unsigned short* Out = (unsigned short*)P;
  const int bm = blockIdx.x * 128, bn = blockIdx.y * 128;
  f32x4 acc[4][4] = {};
  nt_gemm_core(A, BT, D_, bm, bn, As, Bs, acc);
  const int lane = threadIdx.x & 63, w = threadIdx.x >> 6;
  const int wr = w >> 1, wc = w & 1, kb = lane >> 4, fr = lane & 15;
#pragma unroll
  for (int m = 0; m < 4; ++m)
#pragma unroll
    for (int n = 0; n < 4; ++n)
#pragma unroll
      for (int r = 0; r < 4; ++r) {
        int row = bm + wr * 64 + m * 16 + kb * 4 + r;
        int col = bn + wc * 64 + n * 16 + fr;
        Out[(size_t)row * D_ + col] = f2bf(acc[m][n][r]);
      }
}

// ---------------------------------------------------------------------------
// Logits (operand-swapped): GT[k][q] = feat[k,:] . P[q,:]  (= logits[q][k])
// with gate epilogue; fused deg[q] column sums via shuffle + atomicAdd.
// ---------------------------------------------------------------------------
__global__ __launch_bounds__(256) void logits_kernel(
    const __hip_bfloat16* __restrict__ feat, const __hip_bfloat16* __restrict__ P,
    const float* __restrict__ pmask, __hip_bfloat16* __restrict__ GT,
    float* __restrict__ deg) {
  __shared__ short As[4096], Bs[4096];
  const int b = blockIdx.z;
  const unsigned short* A = (const unsigned short*)feat + (size_t)b * N_ * D_;
  const unsigned short* BT = (const unsigned short*)P + (size_t)b * N_ * D_;
  unsigned short* G = (unsigned short*)GT + (size_t)b * N_ * N_;
  const int bm = blockIdx.x * 128, bn = blockIdx.y * 128;
  f32x4 acc[4][4] = {};
  nt_gemm_core(A, BT, D_, bm, bn, As, Bs, acc);
  const int lane = threadIdx.x & 63, w = threadIdx.x >> 6;
  const int wr = w >> 1, wc = w & 1, kb = lane >> 4, fr = lane & 15;
  float colsum[4] = {0.f, 0.f, 0.f, 0.f};
#pragma unroll
  for (int m = 0; m < 4; ++m) {
    float pk[4];
#pragma unroll
    for (int r = 0; r < 4; ++r)
      pk[r] = pmask[b * N_ + bm + wr * 64 + m * 16 + kb * 4 + r];
#pragma unroll
    for (int n = 0; n < 4; ++n) {
      int col = bn + wc * 64 + n * 16 + fr;
      float pq = pmask[b * N_ + col];
#pragma unroll
      for (int r = 0; r < 4; ++r) {
        int row = bm + wr * 64 + m * 16 + kb * 4 + r;
        float x = acc[m][n][r] * kInvSqrtD;
        float s = 1.0f / (1.0f + __expf(-x));
        float g = fminf(fmaxf(s * 1.2f - 0.1f, 0.0f), 1.0f);
        float v = g * pk[r] * pq;
        G[(size_t)row * N_ + col] = f2bf(v);
        colsum[n] += v;
      }
    }
  }
#pragma unroll
  for (int n = 0; n < 4; ++n) {
    float s = colsum[n];
    s += __shfl_xor(s, 16, 64);
    s += __shfl_xor(s, 32, 64);
    if (lane < 16)
      atomicAdd(&deg[b * N_ + bn + wc * 64 + n * 16 + fr], s);
  }
}

// ---------------------------------------------------------------------------
// Aggregation: O[j][d] = dis_j * sum_i GT[j][i] * FT[d][i]  (FT has dis_i
// folded in). Writes fp32 (rows >= 384, for head) and optionally bf16 (L1).
// ---------------------------------------------------------------------------
template <bool WBF>
__global__ __launch_bounds__(256) void agg_kernel(
    const __hip_bfloat16* __restrict__ GT, const __hip_bfloat16* __restrict__ FT,
    const float* __restrict__ dis, float* __restrict__ flast,
    __hip_bfloat16* __restrict__ fbf, int j_off) {
  __shared__ short As[4096], Bs[4096];
  const int b = blockIdx.z;
  const unsigned short* A = (const unsigned short*)GT + (size_t)b * N_ * N_;
  const unsigned short* BT = (const unsigned short*)FT + (size_t)b * D_ * N_;
  const int bm = j_off + blockIdx.x * 128, bn = blockIdx.y * 128;
  f32x4 acc[4][4] = {};
  nt_gemm_core(A, BT, N_, bm, bn, As, Bs, acc);
  const int lane = threadIdx.x & 63, w = threadIdx.x >> 6;
  const int wr = w >> 1, wc = w & 1, kb = lane >> 4, fr = lane & 15;
#pragma unroll
  for (int m = 0; m < 4; ++m) {
#pragma unroll
    for (int r = 0; r < 4; ++r) {
      int row = bm + wr * 64 + m * 16 + kb * 4 + r;
      float dj = dis[b * N_ + row];
#pragma unroll
      for (int n = 0; n < 4; ++n) {
        int col = bn + wc * 64 + n * 16 + fr;
        float v = acc[m][n][r] * dj;
        if (WBF)
          fbf[((size_t)b * N_ + row) * D_ + col] = __float2bfloat16(v);
        if (row >= 384)
          flast[((size_t)b * 128 + row - 384) * D_ + col] = v;
      }
    }
  }
}

// ---------------------------------------------------------------------------
// Transpose + dis-scale: FT[b][d][i] = bf16(dis[b][i] * fin[b][i][d]).
// ---------------------------------------------------------------------------
template <bool BF16IN>
__global__ __launch_bounds__(256) void tscale_kernel(
    const void* __restrict__ fin, const float* __restrict__ dis,
    __hip_bfloat16* __restrict__ FT) {
  __shared__ float Ts[64][65];
  const int b = blockIdx.z;
  const int i0 = blockIdx.x * 64, d0 = blockIdx.y * 64;
  const int t = threadIdx.x;
  const int r16 = t >> 4, c4 = (t & 15) * 4;
#pragma unroll
  for (int p = 0; p < 4; ++p) {
    int i = r16 + p * 16;
    size_t idx = ((size_t)b * N_ + i0 + i) * D_ + d0 + c4;
    float v0, v1, v2, v3;
    if (BF16IN) {
      short4v sv = *reinterpret_cast<const short4v*>((const unsigned short*)fin + idx);
      v0 = bf2f((unsigned short)sv.x); v1 = bf2f((unsigned short)sv.y);
      v2 = bf2f((unsigned short)sv.z); v3 = bf2f((unsigned short)sv.w);
    } else {
      float4 fv = *reinterpret_cast<const float4*>((const float*)fin + idx);
      v0 = fv.x; v1 = fv.y; v2 = fv.z; v3 = fv.w;
    }
    Ts[i][c4 + 0] = v0; Ts[i][c4 + 1] = v1;
    Ts[i][c4 + 2] = v2; Ts[i][c4 + 3] = v3;
  }
  __syncthreads();
#pragma unroll
  for (int q = 0; q < 4; ++q) {
    int d = r16 + q * 16;
    short4v o;
#pragma unroll
    for (int e = 0; e < 4; ++e) {
      float dv = dis[b * N_ + i0 + c4 + e];
      o[e] = (short)f2bf(Ts[c4 + e][d] * dv);
    }
    *reinterpret_cast<short4v*>((unsigned short*)FT + ((size_t)b * D_ + d0 + d) * N_ + i0 + c4) = o;
  }
}

// ---------------------------------------------------------------------------
__global__ __launch_bounds__(256) void cvt_kernel(const float* __restrict__ src,
                                                  __hip_bfloat16* __restrict__ dst) {
  int i = blockIdx.x * 256 + threadIdx.x;
  float4 v = reinterpret_cast<const float4*>(src)[i];
  short4v o = {(short)f2bf(v.x), (short)f2bf(v.y), (short)f2bf(v.z), (short)f2bf(v.w)};
  reinterpret_cast<short4v*>(dst)[i] = o;
}

__global__ __launch_bounds__(256) void dis_kernel(const float* __restrict__ deg,
                                                  float* __restrict__ dis) {
  int i = blockIdx.x * 256 + threadIdx.x;
  float d = deg[i];
  dis[i] = d > 0.0f ? rsqrtf(d) : 0.0f;
}

// ---------------------------------------------------------------------------
// Head (fp32): retain mix at node N-1, then 3-layer MLP. One block per batch.
// ---------------------------------------------------------------------------
__global__ __launch_bounds__(256) void head_kernel(
    const float* __restrict__ feature, const float* __restrict__ f1last,
    const float* __restrict__ f2last, const float* __restrict__ proj_w,
    const float* __restrict__ proj_b, const float* __restrict__ fc1_w,
    const float* __restrict__ fc1_b, const float* __restrict__ fc2_w,
    const float* __restrict__ fc2_b, const float* __restrict__ fcf_w,
    const float* __restrict__ fcf_b, float* __restrict__ out, int branch) {
  const int b = blockIdx.x;
  __shared__ float p[3][D_];
  __shared__ float x[D_];
  __shared__ float h1[FH_];
  __shared__ float h2[FH_];
  __shared__ float retain[3];
  const int tid = threadIdx.x;
  const size_t base0 = ((size_t)b * N_ + (N_ - 1)) * D_;
  const size_t basel = ((size_t)b * 128 + 127) * D_;
  for (int d = tid; d < D_; d += 256) {
    p[0][d] = feature[base0 + d];
    p[1][d] = f1last[basel + d];
    p[2][d] = f2last[basel + d];
  }
  __syncthreads();
  const int w = tid >> 6, lane = tid & 63;
  if (w < 3) {
    float s = 0.0f;
    for (int d = lane; d < D_; d += 64) s += p[w][d] * proj_w[d];
#pragma unroll
    for (int off = 32; off; off >>= 1) s += __shfl_down(s, off, 64);
    if (lane == 0) retain[w] = 1.0f / (1.0f + __expf(-(s + proj_b[0])));
  }
  __syncthreads();
  for (int d = tid; d < D_; d += 256)
    x[d] = retain[0] * p[0][d] + retain[1] * p[1][d] + retain[2] * p[2][d];
  __syncthreads();
  {
    float s = fc1_b[tid];
    const float* wrow = fc1_w + (size_t)tid * D_;
    for (int d = 0; d < D_; ++d) s += wrow[d] * x[d];
    h1[tid] = fmaxf(s, 0.0f);
  }
  __syncthreads();
  {
    float s = fc2_b[tid];
    const float* wrow = fc2_w + (size_t)tid * FH_;
    for (int d = 0; d < FH_; ++d) s += wrow[d] * h1[d];
    h2[tid] = fmaxf(s, 0.0f);
  }
  __syncthreads();
  if (w < NC_) {
    float s = 0.0f;
    for (int g = lane; g < FH_; g += 64) s += h2[g] * fcf_w[(size_t)w * FH_ + g];
#pragma unroll
    for (int off = 32; off; off >>= 1) s += __shfl_down(s, off, 64);
    if (lane == 0) out[((size_t)b * NBR_ + branch) * NC_ + w] = s + fcf_b[w];
  }
}

// ---------------------------------------------------------------------------
extern "C" void kernel_launch(void* const* d_in, const int* in_sizes, int n_in,
                              void* d_out, int out_size, void* d_ws, size_t ws_size,
                              hipStream_t stream) {
  (void)in_sizes; (void)n_in; (void)out_size; (void)ws_size;
  const float* pmask   = (const float*)d_in[0];
  const float* feature = (const float*)d_in[1];
  const float* Wq      = (const float*)d_in[2];
  const float* Wk      = (const float*)d_in[3];
  const float* proj_w  = (const float*)d_in[4];
  const float* proj_b  = (const float*)d_in[5];
  const float* fc1_w   = (const float*)d_in[6];
  const float* fc1_b   = (const float*)d_in[7];
  const float* fc2_w   = (const float*)d_in[8];
  const float* fc2_b   = (const float*)d_in[9];
  const float* fcf_w   = (const float*)d_in[10];
  const float* fcf_b   = (const float*)d_in[11];
  float* out = (float*)d_out;

  const size_t nBND  = (size_t)B_ * N_ * D_;        // 12,582,912
  const size_t nW    = (size_t)NBR_ * L_ * D_ * D_; //  4,718,592
  const size_t nBNN  = (size_t)B_ * N_ * N_;        //  8,388,608
  const size_t nLast = (size_t)B_ * 128 * D_;       //  3,145,728

  char* p = (char*)d_ws;
  __hip_bfloat16* feat0 = (__hip_bfloat16*)p; p += nBND * 2;
  __hip_bfloat16* Wqbf  = (__hip_bfloat16*)p; p += nW * 2;
  __hip_bfloat16* Wkbf  = (__hip_bfloat16*)p; p += nW * 2;
  __hip_bfloat16* MT    = (__hip_bfloat16*)p; p += nW * 2;
  __hip_bfloat16* Pb    = (__hip_bfloat16*)p; p += nBND * 2;
  __hip_bfloat16* GT    = (__hip_bfloat16*)p; p += nBNN * 2;
  __hip_bfloat16* FT    = (__hip_bfloat16*)p; p += nBND * 2;
  __hip_bfloat16* f1bf  = (__hip_bfloat16*)p; p += nBND * 2;
  float* deg    = (float*)p; p += (size_t)B_ * N_ * 4;
  float* dis    = (float*)p; p += (size_t)B_ * N_ * 4;
  float* f1last = (float*)p; p += nLast * 4;
  float* f2last = (float*)p; p += nLast * 4;

  dim3 blk(256);
  cvt_kernel<<<dim3((unsigned)(nBND / 1024)), blk, 0, stream>>>(feature, feat0);
  cvt_kernel<<<dim3((unsigned)(nW / 1024)), blk, 0, stream>>>(Wq, Wqbf);
  cvt_kernel<<<dim3((unsigned)(nW / 1024)), blk, 0, stream>>>(Wk, Wkbf);
  // MT[z] = Wk[z] @ Wq[z]^T for all 8 (branch,layer) pairs in one launch.
  mt_kernel<<<dim3(6, 6, 8), blk, 0, stream>>>(Wkbf, Wqbf, MT);

  for (int i = 0; i < NBR_; ++i) {
    for (int l = 0; l < L_; ++l) {
      const size_t woff = ((size_t)i * L_ + l) * D_ * D_;
      const __hip_bfloat16* featbf = l ? f1bf : feat0;
      hipMemsetAsync(deg, 0, (size_t)B_ * N_ * 4, stream);
      p_kernel<<<dim3(128, 6), blk, 0, stream>>>(featbf, MT + woff, Pb);
      logits_kernel<<<dim3(4, 4, 32), blk, 0, stream>>>(featbf, Pb, pmask, GT, deg);
      dis_kernel<<<dim3(64), blk, 0, stream>>>(deg, dis);
      if (l == 0) {
        tscale_kernel<false><<<dim3(8, 12, 32), blk, 0, stream>>>(feature, dis, FT);
        agg_kernel<true><<<dim3(4, 6, 32), blk, 0, stream>>>(GT, FT, dis, f1last, f1bf, 0);
      } else {
        tscale_kernel<true><<<dim3(8, 12, 32), blk, 0, stream>>>(f1bf, dis, FT);
        agg_kernel<false><<<dim3(1, 6, 32), blk, 0, stream>>>(GT, FT, dis, f2last, nullptr, 384);
      }
    }
    head_kernel<<<dim3(B_), blk, 0, stream>>>(feature, f1last, f2last,
        proj_w + (size_t)i * D_, proj_b + i,
        fc1_w + (size_t)i * FH_ * D_, fc1_b + (size_t)i * FH_,
        fc2_w + (size_t)i * FH_ * FH_, fc2_b + (size_t)i * FH_,
        fcf_w + (size_t)i * NC_ * FH_, fcf_b + (size_t)i * NC_,
        out, i);
  }
}

// Round 4
// 920.047 us; speedup vs baseline: 8.8183x; 1.2065x over previous
//
#include <hip/hip_runtime.h>
#include <hip/hip_bf16.h>
#include <math.h>

#define B_ 32
#define N_ 512
#define D_ 768
#define L_ 2
#define NBR_ 4
#define FH_ 256
#define NC_ 2

typedef __attribute__((ext_vector_type(8))) short short8;
typedef __attribute__((ext_vector_type(4))) short short4v;
typedef __attribute__((ext_vector_type(4))) float f32x4;

static constexpr float kInvSqrtD = 0.03608439182435161f; // 1/sqrt(768)

__device__ __forceinline__ void gl2lds16(const void* g, void* l) {
  __builtin_amdgcn_global_load_lds(
      (const __attribute__((address_space(1))) unsigned int*)g,
      (__attribute__((address_space(3))) unsigned int*)l, 16, 0, 0);
}
__device__ __forceinline__ unsigned short f2bf(float f) {
  __hip_bfloat16 h = __float2bfloat16(f);
  return *reinterpret_cast<unsigned short*>(&h);
}
__device__ __forceinline__ float bf2f(unsigned short u) {
  unsigned int x = ((unsigned int)u) << 16;
  return __builtin_bit_cast(float, x);
}
__device__ __forceinline__ float deg2dis(float d) {
  return d > 0.0f ? rsqrtf(d) : 0.0f;
}

// ---------------------------------------------------------------------------
// Shared NT-GEMM core (verified): C128x128 += A[M,K] * BT[N,K]^T, bf16 in,
// fp32 acc. 256 threads = 4 waves, each wave a 64x64 quadrant (4x4 frags).
// LDS linear [128][32] staged via global_load_lds width-16. UNCHANGED.
// ---------------------------------------------------------------------------
__device__ __forceinline__ void nt_gemm_core(
    const unsigned short* __restrict__ A, const unsigned short* __restrict__ BT,
    int K, int bm, int bn, short* As, short* Bs, f32x4 (&acc)[4][4]) {
  const int tid = threadIdx.x;
  const int lane = tid & 63;
  const int w = tid >> 6, wr = w >> 1, wc = w & 1;
  const int srow = tid >> 2;        // 0..63
  const int scol = (tid & 3) * 8;   // 0,8,16,24
  const int kb = lane >> 4;         // 0..3
  const int fr = lane & 15;
  for (int k0 = 0; k0 < K; k0 += 32) {
    gl2lds16(A + (size_t)(bm + srow) * K + k0 + scol, As + tid * 8);
    gl2lds16(A + (size_t)(bm + 64 + srow) * K + k0 + scol, As + 2048 + tid * 8);
    gl2lds16(BT + (size_t)(bn + srow) * K + k0 + scol, Bs + tid * 8);
    gl2lds16(BT + (size_t)(bn + 64 + srow) * K + k0 + scol, Bs + 2048 + tid * 8);
    __syncthreads();
    short8 a[4], b[4];
#pragma unroll
    for (int m = 0; m < 4; ++m)
      a[m] = *reinterpret_cast<const short8*>(&As[(wr * 64 + m * 16 + fr) * 32 + kb * 8]);
#pragma unroll
    for (int n = 0; n < 4; ++n)
      b[n] = *reinterpret_cast<const short8*>(&Bs[(wc * 64 + n * 16 + fr) * 32 + kb * 8]);
#pragma unroll
    for (int m = 0; m < 4; ++m)
#pragma unroll
      for (int n = 0; n < 4; ++n)
        acc[m][n] = __builtin_amdgcn_mfma_f32_16x16x32_bf16(a[m], b[n], acc[m][n], 0, 0, 0);
    __syncthreads();
  }
}

// ---------------------------------------------------------------------------
// MT precompute: MT[z][e][d] = sum_c Wk[z][e][c] * Wq[z][d][c]  (= M^T where
// M = Wq Wk^T). One launch, z = branch*L+layer. bf16 out.
// ---------------------------------------------------------------------------
__global__ __launch_bounds__(256) void mt_kernel(
    const __hip_bfloat16* __restrict__ Wkbf, const __hip_bfloat16* __restrict__ Wqbf,
    __hip_bfloat16* __restrict__ MT) {
  __shared__ short As[4096], Bs[4096];
  const size_t zoff = (size_t)blockIdx.z * D_ * D_;
  const unsigned short* A = (const unsigned short*)Wkbf + zoff;
  const unsigned short* BT = (const unsigned short*)Wqbf + zoff;
  unsigned short* Out = (unsigned short*)MT + zoff;
  const int bm = blockIdx.x * 128, bn = blockIdx.y * 128;
  f32x4 acc[4][4] = {};
  nt_gemm_core(A, BT, D_, bm, bn, As, Bs, acc);
  const int lane = threadIdx.x & 63, w = threadIdx.x >> 6;
  const int wr = w >> 1, wc = w & 1, kb = lane >> 4, fr = lane & 15;
#pragma unroll
  for (int m = 0; m < 4; ++m)
#pragma unroll
    for (int n = 0; n < 4; ++n)
#pragma unroll
      for (int r = 0; r < 4; ++r) {
        int row = bm + wr * 64 + m * 16 + kb * 4 + r;
        int col = bn + wc * 64 + n * 16 + fr;
        Out[(size_t)row * D_ + col] = f2bf(acc[m][n][r]);
      }
}

// ---------------------------------------------------------------------------
// P = feat @ M  (via NT with BT = MT). bf16 out. Also zeroes deg[] for the
// following logits pass (first 64 blocks of column 0).
// ---------------------------------------------------------------------------
__global__ __launch_bounds__(256) void p_kernel(
    const __hip_bfloat16* __restrict__ feat, const __hip_bfloat16* __restrict__ MT,
    __hip_bfloat16* __restrict__ P, float* __restrict__ deg) {
  __shared__ short As[4096], Bs[4096];
  if (blockIdx.y == 0 && blockIdx.x < 64) {
    deg[blockIdx.x * 256 + threadIdx.x] = 0.0f;  // B_*N_ = 16384 = 64*256
  }
  const unsigned short* A = (const unsigned short*)feat;
  const unsigned short* BT = (const unsigned short*)MT;
  unsigned short* Out = (unsigned short*)P;
  const int bm = blockIdx.x * 128, bn = blockIdx.y * 128;
  f32x4 acc[4][4] = {};
  nt_gemm_core(A, BT, D_, bm, bn, As, Bs, acc);
  const int lane = threadIdx.x & 63, w = threadIdx.x >> 6;
  const int wr = w >> 1, wc = w & 1, kb = lane >> 4, fr = lane & 15;
#pragma unroll
  for (int m = 0; m < 4; ++m)
#pragma unroll
    for (int n = 0; n < 4; ++n)
#pragma unroll
      for (int r = 0; r < 4; ++r) {
        int row = bm + wr * 64 + m * 16 + kb * 4 + r;
        int col = bn + wc * 64 + n * 16 + fr;
        Out[(size_t)row * D_ + col] = f2bf(acc[m][n][r]);
      }
}

// ---------------------------------------------------------------------------
// Logits (operand-swapped): GT[k][q] = feat[k,:] . P[q,:]  (= logits[q][k])
// with gate epilogue; fused deg[q] column sums via shuffle + atomicAdd.
// WFULL=false skips GT stores for rows < 384 (only rows>=384 consumed).
// ---------------------------------------------------------------------------
template <bool WFULL>
__global__ __launch_bounds__(256) void logits_kernel(
    const __hip_bfloat16* __restrict__ feat, const __hip_bfloat16* __restrict__ P,
    const float* __restrict__ pmask, __hip_bfloat16* __restrict__ GT,
    float* __restrict__ deg) {
  __shared__ short As[4096], Bs[4096];
  const int b = blockIdx.z;
  const unsigned short* A = (const unsigned short*)feat + (size_t)b * N_ * D_;
  const unsigned short* BT = (const unsigned short*)P + (size_t)b * N_ * D_;
  unsigned short* G = (unsigned short*)GT + (size_t)b * N_ * N_;
  const int bm = blockIdx.x * 128, bn = blockIdx.y * 128;
  f32x4 acc[4][4] = {};
  nt_gemm_core(A, BT, D_, bm, bn, As, Bs, acc);
  const int lane = threadIdx.x & 63, w = threadIdx.x >> 6;
  const int wr = w >> 1, wc = w & 1, kb = lane >> 4, fr = lane & 15;
  float colsum[4] = {0.f, 0.f, 0.f, 0.f};
#pragma unroll
  for (int m = 0; m < 4; ++m) {
    float pk[4];
#pragma unroll
    for (int r = 0; r < 4; ++r)
      pk[r] = pmask[b * N_ + bm + wr * 64 + m * 16 + kb * 4 + r];
#pragma unroll
    for (int n = 0; n < 4; ++n) {
      int col = bn + wc * 64 + n * 16 + fr;
      float pq = pmask[b * N_ + col];
#pragma unroll
      for (int r = 0; r < 4; ++r) {
        int row = bm + wr * 64 + m * 16 + kb * 4 + r;
        float x = acc[m][n][r] * kInvSqrtD;
        float s = 1.0f / (1.0f + __expf(-x));
        float g = fminf(fmaxf(s * 1.2f - 0.1f, 0.0f), 1.0f);
        float v = g * pk[r] * pq;
        if (WFULL || row >= 384)
          G[(size_t)row * N_ + col] = f2bf(v);
        colsum[n] += v;
      }
    }
  }
#pragma unroll
  for (int n = 0; n < 4; ++n) {
    float s = colsum[n];
    s += __shfl_xor(s, 16, 64);
    s += __shfl_xor(s, 32, 64);
    if (lane < 16)
      atomicAdd(&deg[b * N_ + bn + wc * 64 + n * 16 + fr], s);
  }
}

// ---------------------------------------------------------------------------
// Aggregation: O[j][d] = dis_j * sum_i GT[j][i] * FT[d][i]  (FT has dis_i
// folded in). dis_j computed inline from deg. Writes bf16 full (WBF) and a
// fp32 row-511 side channel for the head.
// ---------------------------------------------------------------------------
template <bool WBF>
__global__ __launch_bounds__(256) void agg_kernel(
    const __hip_bfloat16* __restrict__ GT, const __hip_bfloat16* __restrict__ FT,
    const float* __restrict__ deg, float* __restrict__ flast,
    __hip_bfloat16* __restrict__ fbf, int j_off) {
  __shared__ short As[4096], Bs[4096];
  const int b = blockIdx.z;
  const unsigned short* A = (const unsigned short*)GT + (size_t)b * N_ * N_;
  const unsigned short* BT = (const unsigned short*)FT + (size_t)b * D_ * N_;
  const int bm = j_off + blockIdx.x * 128, bn = blockIdx.y * 128;
  f32x4 acc[4][4] = {};
  nt_gemm_core(A, BT, N_, bm, bn, As, Bs, acc);
  const int lane = threadIdx.x & 63, w = threadIdx.x >> 6;
  const int wr = w >> 1, wc = w & 1, kb = lane >> 4, fr = lane & 15;
#pragma unroll
  for (int m = 0; m < 4; ++m) {
#pragma unroll
    for (int r = 0; r < 4; ++r) {
      int row = bm + wr * 64 + m * 16 + kb * 4 + r;
      float dj = deg2dis(deg[b * N_ + row]);
#pragma unroll
      for (int n = 0; n < 4; ++n) {
        int col = bn + wc * 64 + n * 16 + fr;
        float v = acc[m][n][r] * dj;
        if (WBF)
          fbf[((size_t)b * N_ + row) * D_ + col] = __float2bfloat16(v);
        if (row == N_ - 1)
          flast[(size_t)b * D_ + col] = v;
      }
    }
  }
}

// ---------------------------------------------------------------------------
// One-time bf16 transpose: FT0raw[b][d][i] = feat0[b][i][d].
// ---------------------------------------------------------------------------
__global__ __launch_bounds__(256) void t0_kernel(
    const __hip_bfloat16* __restrict__ feat0, __hip_bfloat16* __restrict__ FT0raw) {
  __shared__ unsigned short Ts[64][68];
  const int b = blockIdx.z;
  const int i0 = blockIdx.x * 64, d0 = blockIdx.y * 64;
  const int t = threadIdx.x;
  const int r16 = t >> 4, c4 = (t & 15) * 4;
  const unsigned short* F = (const unsigned short*)feat0;
  unsigned short* O = (unsigned short*)FT0raw;
#pragma unroll
  for (int p = 0; p < 4; ++p) {
    int i = r16 + p * 16;
    short4v sv = *reinterpret_cast<const short4v*>(&F[((size_t)b * N_ + i0 + i) * D_ + d0 + c4]);
    Ts[i][c4 + 0] = (unsigned short)sv.x; Ts[i][c4 + 1] = (unsigned short)sv.y;
    Ts[i][c4 + 2] = (unsigned short)sv.z; Ts[i][c4 + 3] = (unsigned short)sv.w;
  }
  __syncthreads();
#pragma unroll
  for (int q = 0; q < 4; ++q) {
    int d = r16 + q * 16;
    short4v o;
#pragma unroll
    for (int e = 0; e < 4; ++e) o[e] = (short)Ts[c4 + e][d];
    *reinterpret_cast<short4v*>(&O[((size_t)b * D_ + d0 + d) * N_ + i0 + c4]) = o;
  }
}

// ---------------------------------------------------------------------------
// Per-branch L0 scale: FT[b][d][i] = FT0raw[b][d][i] * dis[b][i] (contiguous).
// ---------------------------------------------------------------------------
__global__ __launch_bounds__(256) void scale_ft_kernel(
    const __hip_bfloat16* __restrict__ FT0raw, const float* __restrict__ deg,
    __hip_bfloat16* __restrict__ FT) {
  const size_t e0 = ((size_t)blockIdx.x * 256 + threadIdx.x) * 8;
  const int b = (int)(e0 / ((size_t)D_ * N_));
  const int i = (int)(e0 % N_);
  const float* dg = deg + b * N_ + i;
  short8 v = *reinterpret_cast<const short8*>((const unsigned short*)FT0raw + e0);
  short8 o;
#pragma unroll
  for (int e = 0; e < 8; ++e)
    o[e] = (short)f2bf(bf2f((unsigned short)v[e]) * deg2dis(dg[e]));
  *reinterpret_cast<short8*>((unsigned short*)FT + e0) = o;
}

// ---------------------------------------------------------------------------
// Transpose + dis-scale (L1): FT[b][d][i] = bf16(dis[b][i] * fin[b][i][d]).
// ---------------------------------------------------------------------------
__global__ __launch_bounds__(256) void tscale_kernel(
    const __hip_bfloat16* __restrict__ fin, const float* __restrict__ deg,
    __hip_bfloat16* __restrict__ FT) {
  __shared__ float Ts[64][65];
  const int b = blockIdx.z;
  const int i0 = blockIdx.x * 64, d0 = blockIdx.y * 64;
  const int t = threadIdx.x;
  const int r16 = t >> 4, c4 = (t & 15) * 4;
  const unsigned short* F = (const unsigned short*)fin;
#pragma unroll
  for (int p = 0; p < 4; ++p) {
    int i = r16 + p * 16;
    short4v sv = *reinterpret_cast<const short4v*>(&F[((size_t)b * N_ + i0 + i) * D_ + d0 + c4]);
    Ts[i][c4 + 0] = bf2f((unsigned short)sv.x);
    Ts[i][c4 + 1] = bf2f((unsigned short)sv.y);
    Ts[i][c4 + 2] = bf2f((unsigned short)sv.z);
    Ts[i][c4 + 3] = bf2f((unsigned short)sv.w);
  }
  __syncthreads();
#pragma unroll
  for (int q = 0; q < 4; ++q) {
    int d = r16 + q * 16;
    short4v o;
#pragma unroll
    for (int e = 0; e < 4; ++e) {
      float dv = deg2dis(deg[b * N_ + i0 + c4 + e]);
      o[e] = (short)f2bf(Ts[c4 + e][d] * dv);
    }
    *reinterpret_cast<short4v*>((unsigned short*)FT + ((size_t)b * D_ + d0 + d) * N_ + i0 + c4) = o;
  }
}

// ---------------------------------------------------------------------------
__global__ __launch_bounds__(256) void cvt_kernel(const float* __restrict__ src,
                                                  __hip_bfloat16* __restrict__ dst) {
  int i = blockIdx.x * 256 + threadIdx.x;
  float4 v = reinterpret_cast<const float4*>(src)[i];
  short4v o = {(short)f2bf(v.x), (short)f2bf(v.y), (short)f2bf(v.z), (short)f2bf(v.w)};
  reinterpret_cast<short4v*>(dst)[i] = o;
}

// ---------------------------------------------------------------------------
// Fused head for ALL (batch, branch) pairs: grid (B_, NBR_).
// ---------------------------------------------------------------------------
__global__ __launch_bounds__(256) void head_all_kernel(
    const float* __restrict__ feature, const float* __restrict__ flast1,
    const float* __restrict__ flast2, const float* __restrict__ proj_w,
    const float* __restrict__ proj_b, const float* __restrict__ fc1_w,
    const float* __restrict__ fc1_b, const float* __restrict__ fc2_w,
    const float* __restrict__ fc2_b, const float* __restrict__ fcf_w,
    const float* __restrict__ fcf_b, float* __restrict__ out) {
  const int b = blockIdx.x, br = blockIdx.y;
  __shared__ float p[3][D_];
  __shared__ float x[D_];
  __shared__ float h1[FH_];
  __shared__ float h2[FH_];
  __shared__ float retain[3];
  const int tid = threadIdx.x;
  const float4* f0 = (const float4*)(feature + ((size_t)b * N_ + (N_ - 1)) * D_);
  const float4* f1 = (const float4*)(flast1 + ((size_t)br * B_ + b) * D_);
  const float4* f2 = (const float4*)(flast2 + ((size_t)br * B_ + b) * D_);
  for (int d4 = tid; d4 < D_ / 4; d4 += 256) {
    *reinterpret_cast<float4*>(&p[0][d4 * 4]) = f0[d4];
    *reinterpret_cast<float4*>(&p[1][d4 * 4]) = f1[d4];
    *reinterpret_cast<float4*>(&p[2][d4 * 4]) = f2[d4];
  }
  __syncthreads();
  const int w = tid >> 6, lane = tid & 63;
  const float* pw = proj_w + (size_t)br * D_;
  if (w < 3) {
    float s = 0.0f;
    for (int d = lane; d < D_; d += 64) s += p[w][d] * pw[d];
#pragma unroll
    for (int off = 32; off; off >>= 1) s += __shfl_down(s, off, 64);
    if (lane == 0) retain[w] = 1.0f / (1.0f + __expf(-(s + proj_b[br])));
  }
  __syncthreads();
  for (int d = tid; d < D_; d += 256)
    x[d] = retain[0] * p[0][d] + retain[1] * p[1][d] + retain[2] * p[2][d];
  __syncthreads();
  {
    const float4* w4 = (const float4*)(fc1_w + ((size_t)br * FH_ + tid) * D_);
    const float4* x4 = (const float4*)x;
    float4 a = {0.f, 0.f, 0.f, 0.f};
#pragma unroll 4
    for (int d4 = 0; d4 < D_ / 4; ++d4) {
      float4 wv = w4[d4], xv = x4[d4];
      a.x += wv.x * xv.x; a.y += wv.y * xv.y;
      a.z += wv.z * xv.z; a.w += wv.w * xv.w;
    }
    float s = a.x + a.y + a.z + a.w + fc1_b[br * FH_ + tid];
    h1[tid] = fmaxf(s, 0.0f);
  }
  __syncthreads();
  {
    const float4* w4 = (const float4*)(fc2_w + ((size_t)br * FH_ + tid) * FH_);
    const float4* x4 = (const float4*)h1;
    float4 a = {0.f, 0.f, 0.f, 0.f};
#pragma unroll 4
    for (int d4 = 0; d4 < FH_ / 4; ++d4) {
      float4 wv = w4[d4], xv = x4[d4];
      a.x += wv.x * xv.x; a.y += wv.y * xv.y;
      a.z += wv.z * xv.z; a.w += wv.w * xv.w;
    }
    float s = a.x + a.y + a.z + a.w + fc2_b[br * FH_ + tid];
    h2[tid] = fmaxf(s, 0.0f);
  }
  __syncthreads();
  if (w < NC_) {
    float s = 0.0f;
    for (int g = lane; g < FH_; g += 64) s += h2[g] * fcf_w[((size_t)br * NC_ + w) * FH_ + g];
#pragma unroll
    for (int off = 32; off; off >>= 1) s += __shfl_down(s, off, 64);
    if (lane == 0) out[((size_t)b * NBR_ + br) * NC_ + w] = s + fcf_b[br * NC_ + w];
  }
}

// ---------------------------------------------------------------------------
extern "C" void kernel_launch(void* const* d_in, const int* in_sizes, int n_in,
                              void* d_out, int out_size, void* d_ws, size_t ws_size,
                              hipStream_t stream) {
  (void)in_sizes; (void)n_in; (void)out_size; (void)ws_size;
  const float* pmask   = (const float*)d_in[0];
  const float* feature = (const float*)d_in[1];
  const float* Wq      = (const float*)d_in[2];
  const float* Wk      = (const float*)d_in[3];
  const float* proj_w  = (const float*)d_in[4];
  const float* proj_b  = (const float*)d_in[5];
  const float* fc1_w   = (const float*)d_in[6];
  const float* fc1_b   = (const float*)d_in[7];
  const float* fc2_w   = (const float*)d_in[8];
  const float* fc2_b   = (const float*)d_in[9];
  const float* fcf_w   = (const float*)d_in[10];
  const float* fcf_b   = (const float*)d_in[11];
  float* out = (float*)d_out;

  const size_t nBND  = (size_t)B_ * N_ * D_;        // 12,582,912
  const size_t nW    = (size_t)NBR_ * L_ * D_ * D_; //  4,718,592
  const size_t nBNN  = (size_t)B_ * N_ * N_;        //  8,388,608

  char* p = (char*)d_ws;
  __hip_bfloat16* feat0  = (__hip_bfloat16*)p; p += nBND * 2;
  __hip_bfloat16* Wqbf   = (__hip_bfloat16*)p; p += nW * 2;
  __hip_bfloat16* Wkbf   = (__hip_bfloat16*)p; p += nW * 2;
  __hip_bfloat16* MT     = (__hip_bfloat16*)p; p += nW * 2;
  __hip_bfloat16* Pb     = (__hip_bfloat16*)p; p += nBND * 2;
  __hip_bfloat16* GT     = (__hip_bfloat16*)p; p += nBNN * 2;
  __hip_bfloat16* FT     = (__hip_bfloat16*)p; p += nBND * 2;
  __hip_bfloat16* FT0raw = (__hip_bfloat16*)p; p += nBND * 2;
  __hip_bfloat16* f1bf   = (__hip_bfloat16*)p; p += nBND * 2;
  float* deg    = (float*)p; p += (size_t)B_ * N_ * 4;
  float* flast1 = (float*)p; p += (size_t)NBR_ * B_ * D_ * 4;
  float* flast2 = (float*)p; p += (size_t)NBR_ * B_ * D_ * 4;

  dim3 blk(256);
  cvt_kernel<<<dim3((unsigned)(nBND / 1024)), blk, 0, stream>>>(feature, feat0);
  cvt_kernel<<<dim3((unsigned)(nW / 1024)), blk, 0, stream>>>(Wq, Wqbf);
  cvt_kernel<<<dim3((unsigned)(nW / 1024)), blk, 0, stream>>>(Wk, Wkbf);
  mt_kernel<<<dim3(6, 6, 8), blk, 0, stream>>>(Wkbf, Wqbf, MT);
  t0_kernel<<<dim3(8, 12, B_), blk, 0, stream>>>(feat0, FT0raw);

  for (int i = 0; i < NBR_; ++i) {
    for (int l = 0; l < L_; ++l) {
      const size_t woff = ((size_t)i * L_ + l) * D_ * D_;
      const __hip_bfloat16* featbf = l ? f1bf : feat0;
      p_kernel<<<dim3(128, 6), blk, 0, stream>>>(featbf, MT + woff, Pb, deg);
      if (l == 0) {
        logits_kernel<true><<<dim3(4, 4, 32), blk, 0, stream>>>(featbf, Pb, pmask, GT, deg);
        scale_ft_kernel<<<dim3((unsigned)(nBND / 2048)), blk, 0, stream>>>(FT0raw, deg, FT);
        agg_kernel<true><<<dim3(4, 6, 32), blk, 0, stream>>>(
            GT, FT, deg, flast1 + (size_t)i * B_ * D_, f1bf, 0);
      } else {
        logits_kernel<false><<<dim3(4, 4, 32), blk, 0, stream>>>(featbf, Pb, pmask, GT, deg);
        tscale_kernel<<<dim3(8, 12, 32), blk, 0, stream>>>(f1bf, deg, FT);
        agg_kernel<false><<<dim3(1, 6, 32), blk, 0, stream>>>(
            GT, FT, deg, flast2 + (size_t)i * B_ * D_, nullptr, 384);
      }
    }
  }
  head_all_kernel<<<dim3(B_, NBR_), blk, 0, stream>>>(
      feature, flast1, flast2, proj_w, proj_b, fc1_w, fc1_b, fc2_w, fc2_b,
      fcf_w, fcf_b, out);
}

// Round 5
// 914.149 us; speedup vs baseline: 8.8752x; 1.0065x over previous
//
#include <hip/hip_runtime.h>
#include <hip/hip_bf16.h>
#include <math.h>

#define B_ 32
#define N_ 512
#define D_ 768
#define L_ 2
#define NBR_ 4
#define FH_ 256
#define NC_ 2
#define BN_   ((size_t)B_ * N_)        // 16384
#define NBND_ ((size_t)B_ * N_ * D_)   // 12,582,912
#define NBNN_ ((size_t)B_ * N_ * N_)   // 8,388,608
#define NW_   ((size_t)NBR_ * L_ * D_ * D_)

typedef __attribute__((ext_vector_type(8))) short short8;
typedef __attribute__((ext_vector_type(4))) short short4v;
typedef __attribute__((ext_vector_type(4))) float f32x4;

static constexpr float kInvSqrtD = 0.03608439182435161f; // 1/sqrt(768)

__device__ __forceinline__ void gl2lds16(const void* g, void* l) {
  __builtin_amdgcn_global_load_lds(
      (const __attribute__((address_space(1))) unsigned int*)g,
      (__attribute__((address_space(3))) unsigned int*)l, 16, 0, 0);
}
__device__ __forceinline__ unsigned short f2bf(float f) {
  __hip_bfloat16 h = __float2bfloat16(f);
  return *reinterpret_cast<unsigned short*>(&h);
}
__device__ __forceinline__ float bf2f(unsigned short u) {
  unsigned int x = ((unsigned int)u) << 16;
  return __builtin_bit_cast(float, x);
}
__device__ __forceinline__ float deg2dis(float d) {
  return d > 0.0f ? rsqrtf(d) : 0.0f;
}

// ---------------------------------------------------------------------------
// Shared NT-GEMM core (verified, UNCHANGED): C128x128 += A[M,K]*BT[N,K]^T.
// ---------------------------------------------------------------------------
__device__ __forceinline__ void nt_gemm_core(
    const unsigned short* __restrict__ A, const unsigned short* __restrict__ BT,
    int K, int bm, int bn, short* As, short* Bs, f32x4 (&acc)[4][4]) {
  const int tid = threadIdx.x;
  const int lane = tid & 63;
  const int w = tid >> 6, wr = w >> 1, wc = w & 1;
  const int srow = tid >> 2;
  const int scol = (tid & 3) * 8;
  const int kb = lane >> 4;
  const int fr = lane & 15;
  for (int k0 = 0; k0 < K; k0 += 32) {
    gl2lds16(A + (size_t)(bm + srow) * K + k0 + scol, As + tid * 8);
    gl2lds16(A + (size_t)(bm + 64 + srow) * K + k0 + scol, As + 2048 + tid * 8);
    gl2lds16(BT + (size_t)(bn + srow) * K + k0 + scol, Bs + tid * 8);
    gl2lds16(BT + (size_t)(bn + 64 + srow) * K + k0 + scol, Bs + 2048 + tid * 8);
    __syncthreads();
    short8 a[4], b[4];
#pragma unroll
    for (int m = 0; m < 4; ++m)
      a[m] = *reinterpret_cast<const short8*>(&As[(wr * 64 + m * 16 + fr) * 32 + kb * 8]);
#pragma unroll
    for (int n = 0; n < 4; ++n)
      b[n] = *reinterpret_cast<const short8*>(&Bs[(wc * 64 + n * 16 + fr) * 32 + kb * 8]);
#pragma unroll
    for (int m = 0; m < 4; ++m)
#pragma unroll
      for (int n = 0; n < 4; ++n)
        acc[m][n] = __builtin_amdgcn_mfma_f32_16x16x32_bf16(a[m], b[n], acc[m][n], 0, 0, 0);
    __syncthreads();
  }
}

// ---------------------------------------------------------------------------
// MT precompute: MT[z] = Wk[z] @ Wq[z]^T, z = branch*L+layer.
// ---------------------------------------------------------------------------
__global__ __launch_bounds__(256) void mt_kernel(
    const __hip_bfloat16* __restrict__ Wkbf, const __hip_bfloat16* __restrict__ Wqbf,
    __hip_bfloat16* __restrict__ MT) {
  __shared__ short As[4096], Bs[4096];
  const size_t zoff = (size_t)blockIdx.z * D_ * D_;
  const unsigned short* A = (const unsigned short*)Wkbf + zoff;
  const unsigned short* BT = (const unsigned short*)Wqbf + zoff;
  unsigned short* Out = (unsigned short*)MT + zoff;
  const int bm = blockIdx.x * 128, bn = blockIdx.y * 128;
  f32x4 acc[4][4] = {};
  nt_gemm_core(A, BT, D_, bm, bn, As, Bs, acc);
  const int lane = threadIdx.x & 63, w = threadIdx.x >> 6;
  const int wr = w >> 1, wc = w & 1, kb = lane >> 4, fr = lane & 15;
#pragma unroll
  for (int m = 0; m < 4; ++m)
#pragma unroll
    for (int n = 0; n < 4; ++n)
#pragma unroll
      for (int r = 0; r < 4; ++r) {
        int row = bm + wr * 64 + m * 16 + kb * 4 + r;
        int col = bn + wc * 64 + n * 16 + fr;
        Out[(size_t)row * D_ + col] = f2bf(acc[m][n][r]);
      }
}

// ---------------------------------------------------------------------------
// P[br] = feat(br) @ M(br,l). Also zeroes deg[br] slice for the next logits.
// blockIdx.z = branch. a_br_stride=0 shares feat across branches (L0).
// ---------------------------------------------------------------------------
__global__ __launch_bounds__(256) void p_kernel(
    const __hip_bfloat16* __restrict__ feat, size_t a_br_stride,
    const __hip_bfloat16* __restrict__ MTl, size_t mt_br_stride,
    __hip_bfloat16* __restrict__ P, float* __restrict__ deg) {
  __shared__ short As[4096], Bs[4096];
  const int br = blockIdx.z;
  if (blockIdx.y == 0 && blockIdx.x < 64)
    deg[br * BN_ + blockIdx.x * 256 + threadIdx.x] = 0.0f;
  const unsigned short* A = (const unsigned short*)feat + (size_t)br * a_br_stride;
  const unsigned short* BT = (const unsigned short*)MTl + (size_t)br * mt_br_stride;
  unsigned short* Out = (unsigned short*)P + (size_t)br * NBND_;
  const int bm = blockIdx.x * 128, bn = blockIdx.y * 128;
  f32x4 acc[4][4] = {};
  nt_gemm_core(A, BT, D_, bm, bn, As, Bs, acc);
  const int lane = threadIdx.x & 63, w = threadIdx.x >> 6;
  const int wr = w >> 1, wc = w & 1, kb = lane >> 4, fr = lane & 15;
#pragma unroll
  for (int m = 0; m < 4; ++m)
#pragma unroll
    for (int n = 0; n < 4; ++n)
#pragma unroll
      for (int r = 0; r < 4; ++r) {
        int row = bm + wr * 64 + m * 16 + kb * 4 + r;
        int col = bn + wc * 64 + n * 16 + fr;
        Out[(size_t)row * D_ + col] = f2bf(acc[m][n][r]);
      }
}

// ---------------------------------------------------------------------------
// Logits (operand-swapped): GT[k][q] = feat[k,:] . P[q,:], gate epilogue,
// fused deg[q] column sums. blockIdx.z = br*32 + b.
// ---------------------------------------------------------------------------
template <bool WFULL>
__global__ __launch_bounds__(256) void logits_kernel(
    const __hip_bfloat16* __restrict__ feat, size_t a_br_stride,
    const __hip_bfloat16* __restrict__ P, const float* __restrict__ pmask,
    __hip_bfloat16* __restrict__ GT, float* __restrict__ deg) {
  __shared__ short As[4096], Bs[4096];
  const int br = blockIdx.z >> 5, b = blockIdx.z & 31;
  const unsigned short* A = (const unsigned short*)feat + (size_t)br * a_br_stride + (size_t)b * N_ * D_;
  const unsigned short* BT = (const unsigned short*)P + (size_t)br * NBND_ + (size_t)b * N_ * D_;
  unsigned short* G = (unsigned short*)GT + (size_t)br * NBNN_ + (size_t)b * N_ * N_;
  float* degb = deg + br * BN_ + b * N_;
  const int bm = blockIdx.x * 128, bn = blockIdx.y * 128;
  f32x4 acc[4][4] = {};
  nt_gemm_core(A, BT, D_, bm, bn, As, Bs, acc);
  const int lane = threadIdx.x & 63, w = threadIdx.x >> 6;
  const int wr = w >> 1, wc = w & 1, kb = lane >> 4, fr = lane & 15;
  float colsum[4] = {0.f, 0.f, 0.f, 0.f};
#pragma unroll
  for (int m = 0; m < 4; ++m) {
    float pk[4];
#pragma unroll
    for (int r = 0; r < 4; ++r)
      pk[r] = pmask[b * N_ + bm + wr * 64 + m * 16 + kb * 4 + r];
#pragma unroll
    for (int n = 0; n < 4; ++n) {
      int col = bn + wc * 64 + n * 16 + fr;
      float pq = pmask[b * N_ + col];
#pragma unroll
      for (int r = 0; r < 4; ++r) {
        int row = bm + wr * 64 + m * 16 + kb * 4 + r;
        float x = acc[m][n][r] * kInvSqrtD;
        float s = 1.0f / (1.0f + __expf(-x));
        float g = fminf(fmaxf(s * 1.2f - 0.1f, 0.0f), 1.0f);
        float v = g * pk[r] * pq;
        if (WFULL || row >= 384)
          G[(size_t)row * N_ + col] = f2bf(v);
        colsum[n] += v;
      }
    }
  }
#pragma unroll
  for (int n = 0; n < 4; ++n) {
    float s = colsum[n];
    s += __shfl_xor(s, 16, 64);
    s += __shfl_xor(s, 32, 64);
    if (lane < 16)
      atomicAdd(&degb[bn + wc * 64 + n * 16 + fr], s);
  }
}

// ---------------------------------------------------------------------------
// Aggregation: O[j][d] = dis_j * sum_i GT[j][i] * FT[d][i] (dis_i in FT).
// blockIdx.z = br*32 + b.
// ---------------------------------------------------------------------------
template <bool WBF>
__global__ __launch_bounds__(256) void agg_kernel(
    const __hip_bfloat16* __restrict__ GT, const __hip_bfloat16* __restrict__ FT,
    const float* __restrict__ deg, float* __restrict__ flast,
    __hip_bfloat16* __restrict__ fbf, int j_off) {
  __shared__ short As[4096], Bs[4096];
  const int br = blockIdx.z >> 5, b = blockIdx.z & 31;
  const unsigned short* A = (const unsigned short*)GT + (size_t)br * NBNN_ + (size_t)b * N_ * N_;
  const unsigned short* BT = (const unsigned short*)FT + (size_t)br * NBND_ + (size_t)b * D_ * N_;
  const float* degb = deg + br * BN_ + b * N_;
  const int bm = j_off + blockIdx.x * 128, bn = blockIdx.y * 128;
  f32x4 acc[4][4] = {};
  nt_gemm_core(A, BT, N_, bm, bn, As, Bs, acc);
  const int lane = threadIdx.x & 63, w = threadIdx.x >> 6;
  const int wr = w >> 1, wc = w & 1, kb = lane >> 4, fr = lane & 15;
#pragma unroll
  for (int m = 0; m < 4; ++m) {
#pragma unroll
    for (int r = 0; r < 4; ++r) {
      int row = bm + wr * 64 + m * 16 + kb * 4 + r;
      float dj = deg2dis(degb[row]);
#pragma unroll
      for (int n = 0; n < 4; ++n) {
        int col = bn + wc * 64 + n * 16 + fr;
        float v = acc[m][n][r] * dj;
        if (WBF)
          fbf[(size_t)br * NBND_ + ((size_t)b * N_ + row) * D_ + col] = __float2bfloat16(v);
        if (row == N_ - 1)
          flast[((size_t)br * B_ + b) * D_ + col] = v;
      }
    }
  }
}

// ---------------------------------------------------------------------------
// One-time bf16 transpose: FT0raw[b][d][i] = feat0[b][i][d].
// ---------------------------------------------------------------------------
__global__ __launch_bounds__(256) void t0_kernel(
    const __hip_bfloat16* __restrict__ feat0, __hip_bfloat16* __restrict__ FT0raw) {
  __shared__ unsigned short Ts[64][68];
  const int b = blockIdx.z;
  const int i0 = blockIdx.x * 64, d0 = blockIdx.y * 64;
  const int t = threadIdx.x;
  const int r16 = t >> 4, c4 = (t & 15) * 4;
  const unsigned short* F = (const unsigned short*)feat0;
  unsigned short* O = (unsigned short*)FT0raw;
#pragma unroll
  for (int p = 0; p < 4; ++p) {
    int i = r16 + p * 16;
    short4v sv = *reinterpret_cast<const short4v*>(&F[((size_t)b * N_ + i0 + i) * D_ + d0 + c4]);
    Ts[i][c4 + 0] = (unsigned short)sv.x; Ts[i][c4 + 1] = (unsigned short)sv.y;
    Ts[i][c4 + 2] = (unsigned short)sv.z; Ts[i][c4 + 3] = (unsigned short)sv.w;
  }
  __syncthreads();
#pragma unroll
  for (int q = 0; q < 4; ++q) {
    int d = r16 + q * 16;
    short4v o;
#pragma unroll
    for (int e = 0; e < 4; ++e) o[e] = (short)Ts[c4 + e][d];
    *reinterpret_cast<short4v*>(&O[((size_t)b * D_ + d0 + d) * N_ + i0 + c4]) = o;
  }
}

// ---------------------------------------------------------------------------
// L0 per-branch scale: FT[br][b][d][i] = FT0raw[b][d][i] * dis[br][b][i].
// grid (6144, NB).
// ---------------------------------------------------------------------------
__global__ __launch_bounds__(256) void scale_ft_kernel(
    const __hip_bfloat16* __restrict__ FT0raw, const float* __restrict__ deg,
    __hip_bfloat16* __restrict__ FT) {
  const int br = blockIdx.y;
  const size_t e0 = ((size_t)blockIdx.x * 256 + threadIdx.x) * 8;
  const int b = (int)(e0 / ((size_t)D_ * N_));
  const int i = (int)(e0 % N_);
  const float* dg = deg + br * BN_ + b * N_ + i;
  short8 v = *reinterpret_cast<const short8*>((const unsigned short*)FT0raw + e0);
  short8 o;
#pragma unroll
  for (int e = 0; e < 8; ++e)
    o[e] = (short)f2bf(bf2f((unsigned short)v[e]) * deg2dis(dg[e]));
  *reinterpret_cast<short8*>((unsigned short*)FT + (size_t)br * NBND_ + e0) = o;
}

// ---------------------------------------------------------------------------
// L1 transpose + dis-scale: FT[br][b][d][i] = dis*f1bf[br][b][i][d].
// blockIdx.z = br*32 + b.
// ---------------------------------------------------------------------------
__global__ __launch_bounds__(256) void tscale_kernel(
    const __hip_bfloat16* __restrict__ fin, const float* __restrict__ deg,
    __hip_bfloat16* __restrict__ FT) {
  __shared__ float Ts[64][65];
  const int br = blockIdx.z >> 5, b = blockIdx.z & 31;
  const int i0 = blockIdx.x * 64, d0 = blockIdx.y * 64;
  const int t = threadIdx.x;
  const int r16 = t >> 4, c4 = (t & 15) * 4;
  const unsigned short* F = (const unsigned short*)fin + (size_t)br * NBND_;
#pragma unroll
  for (int p = 0; p < 4; ++p) {
    int i = r16 + p * 16;
    short4v sv = *reinterpret_cast<const short4v*>(&F[((size_t)b * N_ + i0 + i) * D_ + d0 + c4]);
    Ts[i][c4 + 0] = bf2f((unsigned short)sv.x);
    Ts[i][c4 + 1] = bf2f((unsigned short)sv.y);
    Ts[i][c4 + 2] = bf2f((unsigned short)sv.z);
    Ts[i][c4 + 3] = bf2f((unsigned short)sv.w);
  }
  __syncthreads();
#pragma unroll
  for (int q = 0; q < 4; ++q) {
    int d = r16 + q * 16;
    short4v o;
#pragma unroll
    for (int e = 0; e < 4; ++e) {
      float dv = deg2dis(deg[br * BN_ + b * N_ + i0 + c4 + e]);
      o[e] = (short)f2bf(Ts[c4 + e][d] * dv);
    }
    *reinterpret_cast<short4v*>((unsigned short*)FT + (size_t)br * NBND_ +
                                ((size_t)b * D_ + d0 + d) * N_ + i0 + c4) = o;
  }
}

// ---------------------------------------------------------------------------
__global__ __launch_bounds__(256) void cvt_kernel(const float* __restrict__ src,
                                                  __hip_bfloat16* __restrict__ dst) {
  int i = blockIdx.x * 256 + threadIdx.x;
  float4 v = reinterpret_cast<const float4*>(src)[i];
  short4v o = {(short)f2bf(v.x), (short)f2bf(v.y), (short)f2bf(v.z), (short)f2bf(v.w)};
  reinterpret_cast<short4v*>(dst)[i] = o;
}

// ---------------------------------------------------------------------------
// Fused head, 1024 threads, 4 lanes per output element (latency fix).
// grid (B_, NBR_).
// ---------------------------------------------------------------------------
__global__ __launch_bounds__(1024) void head_all_kernel(
    const float* __restrict__ feature, const float* __restrict__ flast1,
    const float* __restrict__ flast2, const float* __restrict__ proj_w,
    const float* __restrict__ proj_b, const float* __restrict__ fc1_w,
    const float* __restrict__ fc1_b, const float* __restrict__ fc2_w,
    const float* __restrict__ fc2_b, const float* __restrict__ fcf_w,
    const float* __restrict__ fcf_b, float* __restrict__ out) {
  const int b = blockIdx.x, br = blockIdx.y;
  __shared__ float p[3][D_];
  __shared__ float x[D_];
  __shared__ float h1[FH_];
  __shared__ float h2[FH_];
  __shared__ float retain[3];
  const int tid = threadIdx.x;
  const float4* srcs[3] = {
      (const float4*)(feature + ((size_t)b * N_ + (N_ - 1)) * D_),
      (const float4*)(flast1 + ((size_t)br * B_ + b) * D_),
      (const float4*)(flast2 + ((size_t)br * B_ + b) * D_)};
  if (tid < 576) {
    int which = tid / 192, dd = tid % 192;
    *reinterpret_cast<float4*>(&p[which][dd * 4]) = srcs[which][dd];
  }
  __syncthreads();
  const int w = tid >> 6, lane = tid & 63;
  const float* pw = proj_w + (size_t)br * D_;
  if (w < 3) {
    float s = 0.0f;
    for (int d = lane; d < D_; d += 64) s += p[w][d] * pw[d];
#pragma unroll
    for (int off = 32; off; off >>= 1) s += __shfl_down(s, off, 64);
    if (lane == 0) retain[w] = 1.0f / (1.0f + __expf(-(s + proj_b[br])));
  }
  __syncthreads();
  if (tid < D_)
    x[tid] = retain[0] * p[0][tid] + retain[1] * p[1][tid] + retain[2] * p[2][tid];
  __syncthreads();
  {
    const int outn = tid >> 2, part = tid & 3;
    const float4* w4 = (const float4*)(fc1_w + ((size_t)br * FH_ + outn) * D_);
    const float4* x4 = (const float4*)x;
    float4 a = {0.f, 0.f, 0.f, 0.f};
#pragma unroll 4
    for (int k = part; k < D_ / 4; k += 4) {
      float4 wv = w4[k], xv = x4[k];
      a.x += wv.x * xv.x; a.y += wv.y * xv.y;
      a.z += wv.z * xv.z; a.w += wv.w * xv.w;
    }
    float s = a.x + a.y + a.z + a.w;
    s += __shfl_xor(s, 1, 64);
    s += __shfl_xor(s, 2, 64);
    if (part == 0) h1[outn] = fmaxf(s + fc1_b[br * FH_ + outn], 0.0f);
  }
  __syncthreads();
  {
    const int outn = tid >> 2, part = tid & 3;
    const float4* w4 = (const float4*)(fc2_w + ((size_t)br * FH_ + outn) * FH_);
    const float4* x4 = (const float4*)h1;
    float4 a = {0.f, 0.f, 0.f, 0.f};
#pragma unroll 4
    for (int k = part; k < FH_ / 4; k += 4) {
      float4 wv = w4[k], xv = x4[k];
      a.x += wv.x * xv.x; a.y += wv.y * xv.y;
      a.z += wv.z * xv.z; a.w += wv.w * xv.w;
    }
    float s = a.x + a.y + a.z + a.w;
    s += __shfl_xor(s, 1, 64);
    s += __shfl_xor(s, 2, 64);
    if (part == 0) h2[outn] = fmaxf(s + fc2_b[br * FH_ + outn], 0.0f);
  }
  __syncthreads();
  if (w < NC_) {
    float s = 0.0f;
    for (int g = lane; g < FH_; g += 64) s += h2[g] * fcf_w[((size_t)br * NC_ + w) * FH_ + g];
#pragma unroll
    for (int off = 32; off; off >>= 1) s += __shfl_down(s, off, 64);
    if (lane == 0) out[((size_t)b * NBR_ + br) * NC_ + w] = s + fcf_b[br * NC_ + w];
  }
}

// ---------------------------------------------------------------------------
extern "C" void kernel_launch(void* const* d_in, const int* in_sizes, int n_in,
                              void* d_out, int out_size, void* d_ws, size_t ws_size,
                              hipStream_t stream) {
  (void)in_sizes; (void)n_in; (void)out_size;
  const float* pmask   = (const float*)d_in[0];
  const float* feature = (const float*)d_in[1];
  const float* Wq      = (const float*)d_in[2];
  const float* Wk      = (const float*)d_in[3];
  const float* proj_w  = (const float*)d_in[4];
  const float* proj_b  = (const float*)d_in[5];
  const float* fc1_w   = (const float*)d_in[6];
  const float* fc1_b   = (const float*)d_in[7];
  const float* fc2_w   = (const float*)d_in[8];
  const float* fc2_b   = (const float*)d_in[9];
  const float* fcf_w   = (const float*)d_in[10];
  const float* fcf_b   = (const float*)d_in[11];
  float* out = (float*)d_out;

  char* p = (char*)d_ws;
  auto take = [&](size_t bytes) {
    char* q = p; p += (bytes + 255) & ~(size_t)255; return q;
  };
  __hip_bfloat16* feat0  = (__hip_bfloat16*)take(NBND_ * 2);
  __hip_bfloat16* MT     = (__hip_bfloat16*)take(NW_ * 2);
  __hip_bfloat16* FT0raw = (__hip_bfloat16*)take(NBND_ * 2);
  float* deg    = (float*)take(NBR_ * BN_ * 4);
  float* flast1 = (float*)take((size_t)NBR_ * B_ * D_ * 4);
  float* flast2 = (float*)take((size_t)NBR_ * B_ * D_ * 4);
  const size_t base_used = (size_t)(p - (char*)d_ws);
  const size_t perbr = NBND_ * 2 + NBNN_ * 2 + NBND_ * 2 + 3 * 256;
  // Batched path needs 4x per-branch buffers; fall back to sequential if
  // the workspace is too small. ws_size is constant -> same work every call.
  const int NB = (ws_size >= base_used + 4 * perbr + 4096) ? 4 : 1;
  __hip_bfloat16* PbFT = (__hip_bfloat16*)take((size_t)NB * NBND_ * 2); // Pb/FT alias
  __hip_bfloat16* GT   = (__hip_bfloat16*)take((size_t)NB * NBNN_ * 2);
  __hip_bfloat16* f1bf = (__hip_bfloat16*)take((size_t)NB * NBND_ * 2);
  // Wq/Wk bf16 overlay into PbFT region (dead after mt_kernel).
  __hip_bfloat16* Wqbf = PbFT;
  __hip_bfloat16* Wkbf = PbFT + NW_;

  dim3 blk(256);
  cvt_kernel<<<dim3((unsigned)(NBND_ / 1024)), blk, 0, stream>>>(feature, feat0);
  cvt_kernel<<<dim3((unsigned)(NW_ / 1024)), blk, 0, stream>>>(Wq, Wqbf);
  cvt_kernel<<<dim3((unsigned)(NW_ / 1024)), blk, 0, stream>>>(Wk, Wkbf);
  mt_kernel<<<dim3(6, 6, 8), blk, 0, stream>>>(Wkbf, Wqbf, MT);
  t0_kernel<<<dim3(8, 12, B_), blk, 0, stream>>>(feat0, FT0raw);

  if (NB == 4) {
    for (int l = 0; l < L_; ++l) {
      const __hip_bfloat16* featA = l ? f1bf : feat0;
      const size_t astr = l ? NBND_ : 0;
      p_kernel<<<dim3(128, 6, 4), blk, 0, stream>>>(
          featA, astr, MT + (size_t)l * D_ * D_, (size_t)L_ * D_ * D_, PbFT, deg);
      if (l == 0) {
        logits_kernel<true><<<dim3(4, 4, 128), blk, 0, stream>>>(
            featA, astr, PbFT, pmask, GT, deg);
        scale_ft_kernel<<<dim3(6144, 4), blk, 0, stream>>>(FT0raw, deg, PbFT);
        agg_kernel<true><<<dim3(4, 6, 128), blk, 0, stream>>>(
            GT, PbFT, deg, flast1, f1bf, 0);
      } else {
        logits_kernel<false><<<dim3(4, 4, 128), blk, 0, stream>>>(
            featA, astr, PbFT, pmask, GT, deg);
        tscale_kernel<<<dim3(8, 12, 128), blk, 0, stream>>>(f1bf, deg, PbFT);
        agg_kernel<false><<<dim3(1, 6, 128), blk, 0, stream>>>(
            GT, PbFT, deg, flast2, nullptr, 384);
      }
    }
  } else {
    for (int i = 0; i < NBR_; ++i) {
      for (int l = 0; l < L_; ++l) {
        const __hip_bfloat16* featA = l ? f1bf : feat0;
        const __hip_bfloat16* MTil = MT + ((size_t)i * L_ + l) * D_ * D_;
        p_kernel<<<dim3(128, 6, 1), blk, 0, stream>>>(featA, 0, MTil, 0, PbFT, deg);
        if (l == 0) {
          logits_kernel<true><<<dim3(4, 4, 32), blk, 0, stream>>>(
              featA, 0, PbFT, pmask, GT, deg);
          scale_ft_kernel<<<dim3(6144, 1), blk, 0, stream>>>(FT0raw, deg, PbFT);
          agg_kernel<true><<<dim3(4, 6, 32), blk, 0, stream>>>(
              GT, PbFT, deg, flast1 + (size_t)i * B_ * D_, f1bf, 0);
        } else {
          logits_kernel<false><<<dim3(4, 4, 32), blk, 0, stream>>>(
              featA, 0, PbFT, pmask, GT, deg);
          tscale_kernel<<<dim3(8, 12, 32), blk, 0, stream>>>(f1bf, deg, PbFT);
          agg_kernel<false><<<dim3(1, 6, 32), blk, 0, stream>>>(
              GT, PbFT, deg, flast2 + (size_t)i * B_ * D_, nullptr, 384);
        }
      }
    }
  }
  head_all_kernel<<<dim3(B_, NBR_), dim3(1024), 0, stream>>>(
      feature, flast1, flast2, proj_w, proj_b, fc1_w, fc1_b, fc2_w, fc2_b,
      fcf_w, fcf_b, out);
}

// Round 6
// 836.544 us; speedup vs baseline: 9.6986x; 1.0928x over previous
//
#include <hip/hip_runtime.h>
#include <hip/hip_bf16.h>
#include <math.h>

#define B_ 32
#define N_ 512
#define D_ 768
#define L_ 2
#define NBR_ 4
#define FH_ 256
#define NC_ 2
#define BN_   ((size_t)B_ * N_)        // 16384
#define NBND_ ((size_t)B_ * N_ * D_)   // 12,582,912
#define NBNN_ ((size_t)B_ * N_ * N_)   // 8,388,608
#define NW_   ((size_t)NBR_ * L_ * D_ * D_)

typedef __attribute__((ext_vector_type(8))) short short8;
typedef __attribute__((ext_vector_type(4))) short short4v;
typedef __attribute__((ext_vector_type(4))) float f32x4;

static constexpr float kInvSqrtD = 0.03608439182435161f; // 1/sqrt(768)

__device__ __forceinline__ void gl2lds16(const void* g, void* l) {
  __builtin_amdgcn_global_load_lds(
      (const __attribute__((address_space(1))) unsigned int*)g,
      (__attribute__((address_space(3))) unsigned int*)l, 16, 0, 0);
}
__device__ __forceinline__ unsigned short f2bf(float f) {
  __hip_bfloat16 h = __float2bfloat16(f);
  return *reinterpret_cast<unsigned short*>(&h);
}
__device__ __forceinline__ float bf2f(unsigned short u) {
  unsigned int x = ((unsigned int)u) << 16;
  return __builtin_bit_cast(float, x);
}
__device__ __forceinline__ float deg2dis(float d) {
  return d > 0.0f ? rsqrtf(d) : 0.0f;
}

// ---------------------------------------------------------------------------
// NT-GEMM core, BK=64: C128x128 += A[M,K]*BT[N,K]^T. Two K-halves staged as
// separate [128][32] LDS sub-buffers (staging pattern per half identical to
// the verified BK=32 core: lds addr = tid*8, linear in tid). ONE barrier pair
// per 64-K step (was two). As/Bs each 8192 shorts (16 KB).
// ---------------------------------------------------------------------------
__device__ __forceinline__ void nt_gemm_core(
    const unsigned short* __restrict__ A, const unsigned short* __restrict__ BT,
    int K, int bm, int bn, short* As, short* Bs, f32x4 (&acc)[4][4]) {
  const int tid = threadIdx.x;
  const int lane = tid & 63;
  const int w = tid >> 6, wr = w >> 1, wc = w & 1;
  const int srow = tid >> 2;        // 0..63
  const int scol = (tid & 3) * 8;   // 0,8,16,24
  const int kb = lane >> 4;         // 0..3
  const int fr = lane & 15;
  for (int k0 = 0; k0 < K; k0 += 64) {
    // half 0: cols k0..k0+31
    gl2lds16(A + (size_t)(bm + srow) * K + k0 + scol, As + tid * 8);
    gl2lds16(A + (size_t)(bm + 64 + srow) * K + k0 + scol, As + 2048 + tid * 8);
    gl2lds16(BT + (size_t)(bn + srow) * K + k0 + scol, Bs + tid * 8);
    gl2lds16(BT + (size_t)(bn + 64 + srow) * K + k0 + scol, Bs + 2048 + tid * 8);
    // half 1: cols k0+32..k0+63
    gl2lds16(A + (size_t)(bm + srow) * K + k0 + 32 + scol, As + 4096 + tid * 8);
    gl2lds16(A + (size_t)(bm + 64 + srow) * K + k0 + 32 + scol, As + 6144 + tid * 8);
    gl2lds16(BT + (size_t)(bn + srow) * K + k0 + 32 + scol, Bs + 4096 + tid * 8);
    gl2lds16(BT + (size_t)(bn + 64 + srow) * K + k0 + 32 + scol, Bs + 6144 + tid * 8);
    __syncthreads();
#pragma unroll
    for (int h = 0; h < 2; ++h) {
      const short* Ah = As + h * 4096;
      const short* Bh = Bs + h * 4096;
      short8 a[4], b[4];
#pragma unroll
      for (int m = 0; m < 4; ++m)
        a[m] = *reinterpret_cast<const short8*>(&Ah[(wr * 64 + m * 16 + fr) * 32 + kb * 8]);
#pragma unroll
      for (int n = 0; n < 4; ++n)
        b[n] = *reinterpret_cast<const short8*>(&Bh[(wc * 64 + n * 16 + fr) * 32 + kb * 8]);
#pragma unroll
      for (int m = 0; m < 4; ++m)
#pragma unroll
        for (int n = 0; n < 4; ++n)
          acc[m][n] = __builtin_amdgcn_mfma_f32_16x16x32_bf16(a[m], b[n], acc[m][n], 0, 0, 0);
    }
    __syncthreads();
  }
}

// ---------------------------------------------------------------------------
// MT precompute: MT[z] = Wk[z] @ Wq[z]^T, z = branch*L+layer.
// ---------------------------------------------------------------------------
__global__ __launch_bounds__(256) void mt_kernel(
    const __hip_bfloat16* __restrict__ Wkbf, const __hip_bfloat16* __restrict__ Wqbf,
    __hip_bfloat16* __restrict__ MT) {
  __shared__ short As[8192], Bs[8192];
  const size_t zoff = (size_t)blockIdx.z * D_ * D_;
  const unsigned short* A = (const unsigned short*)Wkbf + zoff;
  const unsigned short* BT = (const unsigned short*)Wqbf + zoff;
  unsigned short* Out = (unsigned short*)MT + zoff;
  const int bm = blockIdx.x * 128, bn = blockIdx.y * 128;
  f32x4 acc[4][4] = {};
  nt_gemm_core(A, BT, D_, bm, bn, As, Bs, acc);
  const int lane = threadIdx.x & 63, w = threadIdx.x >> 6;
  const int wr = w >> 1, wc = w & 1, kb = lane >> 4, fr = lane & 15;
#pragma unroll
  for (int m = 0; m < 4; ++m)
#pragma unroll
    for (int n = 0; n < 4; ++n)
#pragma unroll
      for (int r = 0; r < 4; ++r) {
        int row = bm + wr * 64 + m * 16 + kb * 4 + r;
        int col = bn + wc * 64 + n * 16 + fr;
        Out[(size_t)row * D_ + col] = f2bf(acc[m][n][r]);
      }
}

// ---------------------------------------------------------------------------
// P[br] = feat(br) @ M(br,l). Also zeroes deg[br] slice for the next logits.
// blockIdx.z = local branch. a_br_stride=0 shares feat across branches (L0).
// ---------------------------------------------------------------------------
__global__ __launch_bounds__(256) void p_kernel(
    const __hip_bfloat16* __restrict__ feat, size_t a_br_stride,
    const __hip_bfloat16* __restrict__ MTl, size_t mt_br_stride,
    __hip_bfloat16* __restrict__ P, float* __restrict__ deg) {
  __shared__ short As[8192], Bs[8192];
  const int br = blockIdx.z;
  if (blockIdx.y == 0 && blockIdx.x < 64)
    deg[br * BN_ + blockIdx.x * 256 + threadIdx.x] = 0.0f;
  const unsigned short* A = (const unsigned short*)feat + (size_t)br * a_br_stride;
  const unsigned short* BT = (const unsigned short*)MTl + (size_t)br * mt_br_stride;
  unsigned short* Out = (unsigned short*)P + (size_t)br * NBND_;
  const int bm = blockIdx.x * 128, bn = blockIdx.y * 128;
  f32x4 acc[4][4] = {};
  nt_gemm_core(A, BT, D_, bm, bn, As, Bs, acc);
  const int lane = threadIdx.x & 63, w = threadIdx.x >> 6;
  const int wr = w >> 1, wc = w & 1, kb = lane >> 4, fr = lane & 15;
#pragma unroll
  for (int m = 0; m < 4; ++m)
#pragma unroll
    for (int n = 0; n < 4; ++n)
#pragma unroll
      for (int r = 0; r < 4; ++r) {
        int row = bm + wr * 64 + m * 16 + kb * 4 + r;
        int col = bn + wc * 64 + n * 16 + fr;
        Out[(size_t)row * D_ + col] = f2bf(acc[m][n][r]);
      }
}

// ---------------------------------------------------------------------------
// Logits (operand-swapped): GT[k][q] = feat[k,:] . P[q,:], gate epilogue,
// fused deg[q] column sums. blockIdx.z = br*32 + b (br local).
// ---------------------------------------------------------------------------
template <bool WFULL>
__global__ __launch_bounds__(256) void logits_kernel(
    const __hip_bfloat16* __restrict__ feat, size_t a_br_stride,
    const __hip_bfloat16* __restrict__ P, const float* __restrict__ pmask,
    __hip_bfloat16* __restrict__ GT, float* __restrict__ deg) {
  __shared__ short As[8192], Bs[8192];
  const int br = blockIdx.z >> 5, b = blockIdx.z & 31;
  const unsigned short* A = (const unsigned short*)feat + (size_t)br * a_br_stride + (size_t)b * N_ * D_;
  const unsigned short* BT = (const unsigned short*)P + (size_t)br * NBND_ + (size_t)b * N_ * D_;
  unsigned short* G = (unsigned short*)GT + (size_t)br * NBNN_ + (size_t)b * N_ * N_;
  float* degb = deg + br * BN_ + b * N_;
  const int bm = blockIdx.x * 128, bn = blockIdx.y * 128;
  f32x4 acc[4][4] = {};
  nt_gemm_core(A, BT, D_, bm, bn, As, Bs, acc);
  const int lane = threadIdx.x & 63, w = threadIdx.x >> 6;
  const int wr = w >> 1, wc = w & 1, kb = lane >> 4, fr = lane & 15;
  float colsum[4] = {0.f, 0.f, 0.f, 0.f};
#pragma unroll
  for (int m = 0; m < 4; ++m) {
    float pk[4];
#pragma unroll
    for (int r = 0; r < 4; ++r)
      pk[r] = pmask[b * N_ + bm + wr * 64 + m * 16 + kb * 4 + r];
#pragma unroll
    for (int n = 0; n < 4; ++n) {
      int col = bn + wc * 64 + n * 16 + fr;
      float pq = pmask[b * N_ + col];
#pragma unroll
      for (int r = 0; r < 4; ++r) {
        int row = bm + wr * 64 + m * 16 + kb * 4 + r;
        float x = acc[m][n][r] * kInvSqrtD;
        float s = 1.0f / (1.0f + __expf(-x));
        float g = fminf(fmaxf(s * 1.2f - 0.1f, 0.0f), 1.0f);
        float v = g * pk[r] * pq;
        if (WFULL || row >= 384)
          G[(size_t)row * N_ + col] = f2bf(v);
        colsum[n] += v;
      }
    }
  }
#pragma unroll
  for (int n = 0; n < 4; ++n) {
    float s = colsum[n];
    s += __shfl_xor(s, 16, 64);
    s += __shfl_xor(s, 32, 64);
    if (lane < 16)
      atomicAdd(&degb[bn + wc * 64 + n * 16 + fr], s);
  }
}

// ---------------------------------------------------------------------------
// Aggregation: O[j][d] = dis_j * sum_i GT[j][i] * FT[d][i] (dis_i in FT).
// blockIdx.z = br*32 + b (br local).
// ---------------------------------------------------------------------------
template <bool WBF>
__global__ __launch_bounds__(256) void agg_kernel(
    const __hip_bfloat16* __restrict__ GT, const __hip_bfloat16* __restrict__ FT,
    const float* __restrict__ deg, float* __restrict__ flast,
    __hip_bfloat16* __restrict__ fbf, int j_off) {
  __shared__ short As[8192], Bs[8192];
  const int br = blockIdx.z >> 5, b = blockIdx.z & 31;
  const unsigned short* A = (const unsigned short*)GT + (size_t)br * NBNN_ + (size_t)b * N_ * N_;
  const unsigned short* BT = (const unsigned short*)FT + (size_t)br * NBND_ + (size_t)b * D_ * N_;
  const float* degb = deg + br * BN_ + b * N_;
  const int bm = j_off + blockIdx.x * 128, bn = blockIdx.y * 128;
  f32x4 acc[4][4] = {};
  nt_gemm_core(A, BT, N_, bm, bn, As, Bs, acc);
  const int lane = threadIdx.x & 63, w = threadIdx.x >> 6;
  const int wr = w >> 1, wc = w & 1, kb = lane >> 4, fr = lane & 15;
#pragma unroll
  for (int m = 0; m < 4; ++m) {
#pragma unroll
    for (int r = 0; r < 4; ++r) {
      int row = bm + wr * 64 + m * 16 + kb * 4 + r;
      float dj = deg2dis(degb[row]);
#pragma unroll
      for (int n = 0; n < 4; ++n) {
        int col = bn + wc * 64 + n * 16 + fr;
        float v = acc[m][n][r] * dj;
        if (WBF)
          fbf[(size_t)br * NBND_ + ((size_t)b * N_ + row) * D_ + col] = __float2bfloat16(v);
        if (row == N_ - 1)
          flast[((size_t)br * B_ + b) * D_ + col] = v;
      }
    }
  }
}

// ---------------------------------------------------------------------------
// One-time bf16 transpose: FT0raw[b][d][i] = feat0[b][i][d].
// ---------------------------------------------------------------------------
__global__ __launch_bounds__(256) void t0_kernel(
    const __hip_bfloat16* __restrict__ feat0, __hip_bfloat16* __restrict__ FT0raw) {
  __shared__ unsigned short Ts[64][68];
  const int b = blockIdx.z;
  const int i0 = blockIdx.x * 64, d0 = blockIdx.y * 64;
  const int t = threadIdx.x;
  const int r16 = t >> 4, c4 = (t & 15) * 4;
  const unsigned short* F = (const unsigned short*)feat0;
  unsigned short* O = (unsigned short*)FT0raw;
#pragma unroll
  for (int p = 0; p < 4; ++p) {
    int i = r16 + p * 16;
    short4v sv = *reinterpret_cast<const short4v*>(&F[((size_t)b * N_ + i0 + i) * D_ + d0 + c4]);
    Ts[i][c4 + 0] = (unsigned short)sv.x; Ts[i][c4 + 1] = (unsigned short)sv.y;
    Ts[i][c4 + 2] = (unsigned short)sv.z; Ts[i][c4 + 3] = (unsigned short)sv.w;
  }
  __syncthreads();
#pragma unroll
  for (int q = 0; q < 4; ++q) {
    int d = r16 + q * 16;
    short4v o;
#pragma unroll
    for (int e = 0; e < 4; ++e) o[e] = (short)Ts[c4 + e][d];
    *reinterpret_cast<short4v*>(&O[((size_t)b * D_ + d0 + d) * N_ + i0 + c4]) = o;
  }
}

// ---------------------------------------------------------------------------
// L0 per-branch scale: FT[br][b][d][i] = FT0raw[b][d][i] * dis[br][b][i].
// grid (6144, NB).
// ---------------------------------------------------------------------------
__global__ __launch_bounds__(256) void scale_ft_kernel(
    const __hip_bfloat16* __restrict__ FT0raw, const float* __restrict__ deg,
    __hip_bfloat16* __restrict__ FT) {
  const int br = blockIdx.y;
  const size_t e0 = ((size_t)blockIdx.x * 256 + threadIdx.x) * 8;
  const int b = (int)(e0 / ((size_t)D_ * N_));
  const int i = (int)(e0 % N_);
  const float* dg = deg + br * BN_ + b * N_ + i;
  short8 v = *reinterpret_cast<const short8*>((const unsigned short*)FT0raw + e0);
  short8 o;
#pragma unroll
  for (int e = 0; e < 8; ++e)
    o[e] = (short)f2bf(bf2f((unsigned short)v[e]) * deg2dis(dg[e]));
  *reinterpret_cast<short8*>((unsigned short*)FT + (size_t)br * NBND_ + e0) = o;
}

// ---------------------------------------------------------------------------
// L1 transpose + dis-scale: FT[br][b][d][i] = dis*f1bf[br][b][i][d].
// blockIdx.z = br*32 + b (br local).
// ---------------------------------------------------------------------------
__global__ __launch_bounds__(256) void tscale_kernel(
    const __hip_bfloat16* __restrict__ fin, const float* __restrict__ deg,
    __hip_bfloat16* __restrict__ FT) {
  __shared__ float Ts[64][65];
  const int br = blockIdx.z >> 5, b = blockIdx.z & 31;
  const int i0 = blockIdx.x * 64, d0 = blockIdx.y * 64;
  const int t = threadIdx.x;
  const int r16 = t >> 4, c4 = (t & 15) * 4;
  const unsigned short* F = (const unsigned short*)fin + (size_t)br * NBND_;
#pragma unroll
  for (int p = 0; p < 4; ++p) {
    int i = r16 + p * 16;
    short4v sv = *reinterpret_cast<const short4v*>(&F[((size_t)b * N_ + i0 + i) * D_ + d0 + c4]);
    Ts[i][c4 + 0] = bf2f((unsigned short)sv.x);
    Ts[i][c4 + 1] = bf2f((unsigned short)sv.y);
    Ts[i][c4 + 2] = bf2f((unsigned short)sv.z);
    Ts[i][c4 + 3] = bf2f((unsigned short)sv.w);
  }
  __syncthreads();
#pragma unroll
  for (int q = 0; q < 4; ++q) {
    int d = r16 + q * 16;
    short4v o;
#pragma unroll
    for (int e = 0; e < 4; ++e) {
      float dv = deg2dis(deg[br * BN_ + b * N_ + i0 + c4 + e]);
      o[e] = (short)f2bf(Ts[c4 + e][d] * dv);
    }
    *reinterpret_cast<short4v*>((unsigned short*)FT + (size_t)br * NBND_ +
                                ((size_t)b * D_ + d0 + d) * N_ + i0 + c4) = o;
  }
}

// ---------------------------------------------------------------------------
__global__ __launch_bounds__(256) void cvt_kernel(const float* __restrict__ src,
                                                  __hip_bfloat16* __restrict__ dst) {
  int i = blockIdx.x * 256 + threadIdx.x;
  float4 v = reinterpret_cast<const float4*>(src)[i];
  short4v o = {(short)f2bf(v.x), (short)f2bf(v.y), (short)f2bf(v.z), (short)f2bf(v.w)};
  reinterpret_cast<short4v*>(dst)[i] = o;
}

// ---------------------------------------------------------------------------
// Fused head, 1024 threads, 4 lanes per output element. grid (B_, NBR_).
// ---------------------------------------------------------------------------
__global__ __launch_bounds__(1024) void head_all_kernel(
    const float* __restrict__ feature, const float* __restrict__ flast1,
    const float* __restrict__ flast2, const float* __restrict__ proj_w,
    const float* __restrict__ proj_b, const float* __restrict__ fc1_w,
    const float* __restrict__ fc1_b, const float* __restrict__ fc2_w,
    const float* __restrict__ fc2_b, const float* __restrict__ fcf_w,
    const float* __restrict__ fcf_b, float* __restrict__ out) {
  const int b = blockIdx.x, br = blockIdx.y;
  __shared__ float p[3][D_];
  __shared__ float x[D_];
  __shared__ float h1[FH_];
  __shared__ float h2[FH_];
  __shared__ float retain[3];
  const int tid = threadIdx.x;
  const float4* srcs[3] = {
      (const float4*)(feature + ((size_t)b * N_ + (N_ - 1)) * D_),
      (const float4*)(flast1 + ((size_t)br * B_ + b) * D_),
      (const float4*)(flast2 + ((size_t)br * B_ + b) * D_)};
  if (tid < 576) {
    int which = tid / 192, dd = tid % 192;
    *reinterpret_cast<float4*>(&p[which][dd * 4]) = srcs[which][dd];
  }
  __syncthreads();
  const int w = tid >> 6, lane = tid & 63;
  const float* pw = proj_w + (size_t)br * D_;
  if (w < 3) {
    float s = 0.0f;
    for (int d = lane; d < D_; d += 64) s += p[w][d] * pw[d];
#pragma unroll
    for (int off = 32; off; off >>= 1) s += __shfl_down(s, off, 64);
    if (lane == 0) retain[w] = 1.0f / (1.0f + __expf(-(s + proj_b[br])));
  }
  __syncthreads();
  if (tid < D_)
    x[tid] = retain[0] * p[0][tid] + retain[1] * p[1][tid] + retain[2] * p[2][tid];
  __syncthreads();
  {
    const int outn = tid >> 2, part = tid & 3;
    const float4* w4 = (const float4*)(fc1_w + ((size_t)br * FH_ + outn) * D_);
    const float4* x4 = (const float4*)x;
    float4 a = {0.f, 0.f, 0.f, 0.f};
#pragma unroll 4
    for (int k = part; k < D_ / 4; k += 4) {
      float4 wv = w4[k], xv = x4[k];
      a.x += wv.x * xv.x; a.y += wv.y * xv.y;
      a.z += wv.z * xv.z; a.w += wv.w * xv.w;
    }
    float s = a.x + a.y + a.z + a.w;
    s += __shfl_xor(s, 1, 64);
    s += __shfl_xor(s, 2, 64);
    if (part == 0) h1[outn] = fmaxf(s + fc1_b[br * FH_ + outn], 0.0f);
  }
  __syncthreads();
  {
    const int outn = tid >> 2, part = tid & 3;
    const float4* w4 = (const float4*)(fc2_w + ((size_t)br * FH_ + outn) * FH_);
    const float4* x4 = (const float4*)h1;
    float4 a = {0.f, 0.f, 0.f, 0.f};
#pragma unroll 4
    for (int k = part; k < FH_ / 4; k += 4) {
      float4 wv = w4[k], xv = x4[k];
      a.x += wv.x * xv.x; a.y += wv.y * xv.y;
      a.z += wv.z * xv.z; a.w += wv.w * xv.w;
    }
    float s = a.x + a.y + a.z + a.w;
    s += __shfl_xor(s, 1, 64);
    s += __shfl_xor(s, 2, 64);
    if (part == 0) h2[outn] = fmaxf(s + fc2_b[br * FH_ + outn], 0.0f);
  }
  __syncthreads();
  if (w < NC_) {
    float s = 0.0f;
    for (int g = lane; g < FH_; g += 64) s += h2[g] * fcf_w[((size_t)br * NC_ + w) * FH_ + g];
#pragma unroll
    for (int off = 32; off; off >>= 1) s += __shfl_down(s, off, 64);
    if (lane == 0) out[((size_t)b * NBR_ + w) * NC_ + w] = 0.0f; // (never taken; see below)
  }
  // NOTE: the line above is dead (w<NC_ and lane==0 writes handled next);
  // kept simple: real write below.
  if (w < NC_) {
    float s = 0.0f;
    for (int g = lane; g < FH_; g += 64) s += h2[g] * fcf_w[((size_t)br * NC_ + w) * FH_ + g];
#pragma unroll
    for (int off = 32; off; off >>= 1) s += __shfl_down(s, off, 64);
    if (lane == 0) out[((size_t)b * NBR_ + br) * NC_ + w] = s + fcf_b[br * NC_ + w];
  }
}

// ---------------------------------------------------------------------------
extern "C" void kernel_launch(void* const* d_in, const int* in_sizes, int n_in,
                              void* d_out, int out_size, void* d_ws, size_t ws_size,
                              hipStream_t stream) {
  (void)in_sizes; (void)n_in; (void)out_size;
  const float* pmask   = (const float*)d_in[0];
  const float* feature = (const float*)d_in[1];
  const float* Wq      = (const float*)d_in[2];
  const float* Wk      = (const float*)d_in[3];
  const float* proj_w  = (const float*)d_in[4];
  const float* proj_b  = (const float*)d_in[5];
  const float* fc1_w   = (const float*)d_in[6];
  const float* fc1_b   = (const float*)d_in[7];
  const float* fc2_w   = (const float*)d_in[8];
  const float* fc2_b   = (const float*)d_in[9];
  const float* fcf_w   = (const float*)d_in[10];
  const float* fcf_b   = (const float*)d_in[11];
  float* out = (float*)d_out;

  char* p = (char*)d_ws;
  auto take = [&](size_t bytes) {
    char* q = p; p += (bytes + 255) & ~(size_t)255; return q;
  };
  __hip_bfloat16* feat0  = (__hip_bfloat16*)take(NBND_ * 2);
  __hip_bfloat16* MT     = (__hip_bfloat16*)take(NW_ * 2);
  __hip_bfloat16* FT0raw = (__hip_bfloat16*)take(NBND_ * 2);
  float* deg    = (float*)take(NBR_ * BN_ * 4);
  float* flast1 = (float*)take((size_t)NBR_ * B_ * D_ * 4);
  float* flast2 = (float*)take((size_t)NBR_ * B_ * D_ * 4);
  const size_t base_used = (size_t)(p - (char*)d_ws);
  const size_t perbr = NBND_ * 2 + NBNN_ * 2 + NBND_ * 2 + 3 * 256;
  // Largest branch-batch that fits the workspace (ws_size is constant per
  // problem -> identical path & work on every call).
  int NB = 1;
  if (ws_size >= base_used + 4 * perbr + 4096) NB = 4;
  else if (ws_size >= base_used + 2 * perbr + 4096) NB = 2;
  __hip_bfloat16* PbFT = (__hip_bfloat16*)take((size_t)NB * NBND_ * 2); // Pb/FT alias
  __hip_bfloat16* GT   = (__hip_bfloat16*)take((size_t)NB * NBNN_ * 2);
  __hip_bfloat16* f1bf = (__hip_bfloat16*)take((size_t)NB * NBND_ * 2);
  // Wq/Wk bf16 overlay into PbFT region (dead after mt_kernel). PbFT holds
  // >= 24 MiB even at NB=1, >= 2*NW_*2 = 18.9 MiB needed.
  __hip_bfloat16* Wqbf = PbFT;
  __hip_bfloat16* Wkbf = PbFT + NW_;

  dim3 blk(256);
  cvt_kernel<<<dim3((unsigned)(NBND_ / 1024)), blk, 0, stream>>>(feature, feat0);
  cvt_kernel<<<dim3((unsigned)(NW_ / 1024)), blk, 0, stream>>>(Wq, Wqbf);
  cvt_kernel<<<dim3((unsigned)(NW_ / 1024)), blk, 0, stream>>>(Wk, Wkbf);
  mt_kernel<<<dim3(6, 6, 8), blk, 0, stream>>>(Wkbf, Wqbf, MT);
  t0_kernel<<<dim3(8, 12, B_), blk, 0, stream>>>(feat0, FT0raw);

  const int NH = NBR_ / NB;
  for (int h = 0; h < NH; ++h) {
    const int brbase = h * NB;
    for (int l = 0; l < L_; ++l) {
      const __hip_bfloat16* featA = l ? f1bf : feat0;
      const size_t astr = l ? NBND_ : 0;
      const __hip_bfloat16* MTl = MT + ((size_t)(brbase * L_ + l)) * D_ * D_;
      p_kernel<<<dim3(128, 6, NB), blk, 0, stream>>>(
          featA, astr, MTl, (size_t)L_ * D_ * D_, PbFT, deg);
      if (l == 0) {
        logits_kernel<true><<<dim3(4, 4, NB * 32), blk, 0, stream>>>(
            featA, astr, PbFT, pmask, GT, deg);
        scale_ft_kernel<<<dim3(6144, NB), blk, 0, stream>>>(FT0raw, deg, PbFT);
        agg_kernel<true><<<dim3(4, 6, NB * 32), blk, 0, stream>>>(
            GT, PbFT, deg, flast1 + (size_t)brbase * B_ * D_, f1bf, 0);
      } else {
        logits_kernel<false><<<dim3(4, 4, NB * 32), blk, 0, stream>>>(
            featA, astr, PbFT, pmask, GT, deg);
        tscale_kernel<<<dim3(8, 12, NB * 32), blk, 0, stream>>>(f1bf, deg, PbFT);
        agg_kernel<false><<<dim3(1, 6, NB * 32), blk, 0, stream>>>(
            GT, PbFT, deg, flast2 + (size_t)brbase * B_ * D_, nullptr, 384);
      }
    }
  }
  head_all_kernel<<<dim3(B_, NBR_), dim3(1024), 0, stream>>>(
      feature, flast1, flast2, proj_w, proj_b, fc1_w, fc1_b, fc2_w, fc2_b,
      fcf_w, fcf_b, out);
}